// Round 2
// baseline (41575.412 us; speedup 1.0000x reference)
//
#include <hip/hip_runtime.h>
#include <cstddef>

// ConvLSTM cell, fp32 direct conv, BN-stat fusion, reg-staged LDS double-buffer.
// Gate conv: one 1024-thread block computes all 4 gates from one shared input tile,
// with x_emb's BN folded into pre-scaled weights + bias (pad = mean trick).

typedef float f4 __attribute__((ext_vector_type(4)));

#define H_   512
#define W_   512
#define HW_  (H_ * W_)
#define EPS_ 1e-5f
#define RMH  518
#define RMHW (RMH * RMH)
#define TS   16

static __device__ __forceinline__ float sigmoidf_(float x) { return 1.f / (1.f + expf(-x)); }

// ---- weight transpose: [COUT][CIN][3][3] -> [CIN*9][COUT] ----
__global__ void wtrans_kernel(const float* __restrict__ src, float* __restrict__ dst,
                              int cin, int cout) {
    int n = cout * cin * 9;
    int idx = blockIdx.x * 256 + threadIdx.x;
    if (idx < n) {
        int co = idx / (cin * 9);
        int r  = idx - co * cin * 9;
        dst[r * cout + co] = src[idx];
    }
}

// ---- fold BN(x_emb) into gate weights (in place) + bias; 128 threads = (z,co) ----
__global__ void wgprep_kernel(float* __restrict__ wt, const float* __restrict__ S2,
                              float* __restrict__ bias) {
    int tid = threadIdx.x;
    int z = tid >> 5, co = tid & 31;
    __shared__ float m_[32], is_[32];
    if (tid < 32) {
        float s = S2[tid * 2], ss = S2[tid * 2 + 1];
        float m = s * (1.f / HW_);
        m_[tid] = m;
        is_[tid] = rsqrtf(ss * (1.f / HW_) - m * m + EPS_);
    }
    __syncthreads();
    float b = 0.f;
    float* wz = wt + (size_t)z * 64 * 9 * 32;
    for (int ci = 32; ci < 64; ++ci) {
        float m = m_[ci - 32], is = is_[ci - 32];
        for (int k = 0; k < 9; ++k) {
            size_t idx = (size_t)(ci * 9 + k) * 32 + co;
            float w = wz[idx] * is;
            wz[idx] = w;
            b -= m * w;   // cancels the pad=mean substitution at borders
        }
    }
    bias[tid] = b;
}

// ---- generic direct 3x3 conv, 16x16 tile, reg-staged LDS dbuf ----
// MODE: 0 = raw input; 2 = BN-normalize + relu at LDS-write time.
template <int CIN, int COUT, int PAD, int MODE>
__global__ __launch_bounds__(256) void conv3x3_kernel(
    const float* __restrict__ in, const float* __restrict__ sums,
    const float* __restrict__ wt, float* __restrict__ out,
    float* __restrict__ partials, int OH, int OW, float inv_n_in)
{
    constexpr int CH   = (CIN < 8) ? CIN : 8;
    constexpr int NCH  = CIN / CH;
    constexpr int NB   = (NCH > 1) ? 2 : 1;
    constexpr int NELE = CH * 324;
    constexpr int NREG = (NELE + 255) / 256;
    constexpr int NCA  = (MODE == 2) ? CIN : 1;

    __shared__ float smem[NB][NELE];
    __shared__ float s_mean[NCA], s_istd[NCA];
    __shared__ float red[4][COUT][2];

    const int tid = threadIdx.x;
    const int tx = tid & 15, ty = tid >> 4;
    const int bx = blockIdx.x, by = blockIdx.y;

    if constexpr (MODE == 2) {
        if (tid < CIN) {
            float s = sums[tid * 2], ss = sums[tid * 2 + 1];
            float m = s * inv_n_in;
            s_mean[tid] = m;
            s_istd[tid] = rsqrtf(ss * inv_n_in - m * m + EPS_);
        }
        __syncthreads();
    }

    float stg[NREG];

    auto load_chunk = [&](int cc) {
#pragma unroll
        for (int r = 0; r < NREG; ++r) {
            int i = tid + r * 256;
            if (i < NELE) {
                int ci = i / 324;
                int rem = i - ci * 324;
                int ly = rem / 18, lx = rem - ly * 18;
                int gy = by * TS + ly - PAD, gx = bx * TS + lx - PAD;
                int c = cc * CH + ci;
                float v;
                if ((unsigned)gy < 512u && (unsigned)gx < 512u)
                    v = in[(size_t)c * HW_ + gy * 512 + gx];
                else
                    v = (MODE == 2) ? s_mean[c] : 0.f;  // pad: mean -> normalizes to 0
                stg[r] = v;
            }
        }
    };
    auto write_chunk = [&](int cc, int buf) {
#pragma unroll
        for (int r = 0; r < NREG; ++r) {
            int i = tid + r * 256;
            if (i < NELE) {
                float v = stg[r];
                if constexpr (MODE == 2) {
                    int ci = i / 324;
                    int c = cc * CH + ci;
                    v = fmaxf((v - s_mean[c]) * s_istd[c], 0.f);
                }
                smem[buf][i] = v;
            }
        }
    };

    float acc[COUT];
#pragma unroll
    for (int i = 0; i < COUT; ++i) acc[i] = 0.f;

    load_chunk(0);
    write_chunk(0, 0);
    __syncthreads();

#pragma unroll 1
    for (int cc = 0; cc < NCH; ++cc) {
        if (cc + 1 < NCH) load_chunk(cc + 1);          // issue early: latency under compute
        const float* sp = smem[(NB == 1) ? 0 : (cc & 1)];
        const float* wc = wt + (size_t)cc * CH * 9 * COUT;
#pragma unroll
        for (int ci = 0; ci < CH; ++ci) {
#pragma unroll
            for (int kk = 0; kk < 9; ++kk) {
                const int ky = kk / 3, kx = kk - ky * 3;
                float v = sp[ci * 324 + (ty + ky) * 18 + (tx + kx)];
                const float* w = wc + (ci * 9 + kk) * COUT;
#pragma unroll
                for (int co = 0; co < COUT; ++co)
                    acc[co] = fmaf(v, w[co], acc[co]);
            }
        }
        if (cc + 1 < NCH) write_chunk(cc + 1, 1 - (cc & 1));
        __syncthreads();
    }

    const int oy = by * TS + ty, ox = bx * TS + tx;
    const bool valid = (oy < OH) && (ox < OW);
    if (valid) {
#pragma unroll
        for (int co = 0; co < COUT; ++co)
            out[(size_t)co * OH * OW + oy * OW + ox] = acc[co];
    }

    const float scale = valid ? 1.f : 0.f;
    const int wave = tid >> 6, lane = tid & 63;
#pragma unroll
    for (int co = 0; co < COUT; ++co) {
        float s = acc[co] * scale;
        float ss = acc[co] * acc[co] * scale;
#pragma unroll
        for (int o = 32; o > 0; o >>= 1) {
            s += __shfl_down(s, o);
            ss += __shfl_down(ss, o);
        }
        if (lane == 0) { red[wave][co][0] = s; red[wave][co][1] = ss; }
    }
    __syncthreads();
    if (tid < COUT) {
        float s = red[0][tid][0] + red[1][tid][0] + red[2][tid][0] + red[3][tid][0];
        float ss = red[0][tid][1] + red[1][tid][1] + red[2][tid][1] + red[3][tid][1];
        int bl = by * gridDim.x + bx;
        partials[((size_t)bl * COUT + tid) * 2]     = s;
        partials[((size_t)bl * COUT + tid) * 2 + 1] = ss;
    }
}

// ---- fused 4-gate conv: 1024 threads = 256 pixels x 4 gates, one shared input tile ----
__global__ __launch_bounds__(1024) void conv_gates_kernel(
    const float* __restrict__ ph, const float* __restrict__ y2,
    const float* __restrict__ S2, const float* __restrict__ wt,
    const float* __restrict__ bias, float* __restrict__ out,
    float* __restrict__ partials)
{
    __shared__ float smem[2][2592];      // 8ch x 18x18
    __shared__ float s_pad[64];          // border fill: 0 for prev_h, mean2 for x_emb
    __shared__ float red[16][32][2];

    const int tid = threadIdx.x;
    const int tx = tid & 15, ty = (tid >> 4) & 15, z = tid >> 8;
    const int bx = blockIdx.x, by = blockIdx.y;

    if (tid < 64) {
        float pv = 0.f;
        if (tid >= 32) {
            float s = S2[(tid - 32) * 2];
            pv = s * (1.f / HW_);
        }
        s_pad[tid] = pv;
    }

    // loop-invariant fill indexing (3 elems/thread, 2592 total)
    int off[3], cidx[3];
    float stg[3];
#pragma unroll
    for (int r = 0; r < 3; ++r) {
        int i = tid + r * 1024;
        if (i < 2592) {
            int ci = i / 324;
            int rem = i - ci * 324;
            int ly = rem / 18, lx = rem - ly * 18;
            int gy = by * TS + ly - 1, gx = bx * TS + lx - 1;
            cidx[r] = ci;
            off[r] = ((unsigned)gy < 512u && (unsigned)gx < 512u) ? gy * 512 + gx : -1;
        } else { off[r] = -1; cidx[r] = 0; }
    }

    // prologue: chunk 0 (channels 0..7 -> prev_h)
#pragma unroll
    for (int r = 0; r < 3; ++r) {
        stg[r] = 0.f;
        if (off[r] >= 0) stg[r] = ph[(size_t)cidx[r] * HW_ + off[r]];
    }
    __syncthreads();                      // s_pad ready
#pragma unroll
    for (int r = 0; r < 3; ++r) {
        int i = tid + r * 1024;
        if (i < 2592) smem[0][i] = (off[r] >= 0) ? stg[r] : s_pad[cidx[r]];
    }
    __syncthreads();

    float acc[32];
#pragma unroll
    for (int co = 0; co < 32; ++co) acc[co] = bias[z * 32 + co];

    const float* wz = wt + (size_t)z * 64 * 9 * 32;

#pragma unroll 1
    for (int cc = 0; cc < 8; ++cc) {
        if (cc < 7) {                     // issue next chunk's loads before compute
#pragma unroll
            for (int r = 0; r < 3; ++r) {
                stg[r] = 0.f;
                if (off[r] >= 0) {
                    int c = (cc + 1) * 8 + cidx[r];
                    const float* src;
                    size_t base;
                    if (c < 32) { src = ph; base = (size_t)c * HW_; }
                    else        { src = y2; base = (size_t)(c - 32) * HW_; }
                    stg[r] = src[base + off[r]];
                }
            }
        }
        const float* sp = smem[cc & 1];
        const float* wc = wz + cc * 8 * 9 * 32;
#pragma unroll
        for (int ci = 0; ci < 8; ++ci) {
#pragma unroll
            for (int kk = 0; kk < 9; ++kk) {
                const int ky = kk / 3, kx = kk - ky * 3;
                float v = sp[ci * 324 + (ty + ky) * 18 + (tx + kx)];
                const float* w = wc + (ci * 9 + kk) * 32;
#pragma unroll
                for (int co = 0; co < 32; ++co)
                    acc[co] = fmaf(v, w[co], acc[co]);
            }
        }
        if (cc < 7) {
            float* sd = smem[1 - (cc & 1)];
#pragma unroll
            for (int r = 0; r < 3; ++r) {
                int i = tid + r * 1024;
                int c = (cc + 1) * 8 + cidx[r];
                if (i < 2592) sd[i] = (off[r] >= 0) ? stg[r] : s_pad[c];
            }
        }
        __syncthreads();
    }

    const int oy = by * TS + ty, ox = bx * TS + tx;
    const size_t p = (size_t)oy * 512 + ox;
    float* oz = out + (size_t)z * 32 * HW_;
#pragma unroll
    for (int co = 0; co < 32; ++co)
        oz[(size_t)co * HW_ + p] = acc[co];

    const int wave = tid >> 6, lane = tid & 63;
#pragma unroll
    for (int co = 0; co < 32; ++co) {
        float s = acc[co];
        float ss = acc[co] * acc[co];
#pragma unroll
        for (int o = 32; o > 0; o >>= 1) {
            s += __shfl_down(s, o);
            ss += __shfl_down(ss, o);
        }
        if (lane == 0) { red[wave][co][0] = s; red[wave][co][1] = ss; }
    }
    __syncthreads();
    if (tid < 128) {
        int z2 = tid >> 5, co = tid & 31;
        float s = 0.f, ss = 0.f;
#pragma unroll
        for (int w = 0; w < 4; ++w) {
            s += red[z2 * 4 + w][co][0];
            ss += red[z2 * 4 + w][co][1];
        }
        int bl = z2 * 1024 + by * 32 + bx;
        partials[((size_t)bl * 32 + co) * 2]     = s;
        partials[((size_t)bl * 32 + co) * 2 + 1] = ss;
    }
}

// ---- reduce per-block partials -> per-channel (sum, sumsq) ----
__global__ __launch_bounds__(256) void reduce_kernel(const float* __restrict__ p,
                                                     float* __restrict__ sums,
                                                     int nb, int cout) {
    int c = blockIdx.x;
    int g = c / cout, co = c - g * cout;
    const float* base = p + (size_t)g * nb * cout * 2;
    float s = 0.f, ss = 0.f;
    for (int i = threadIdx.x; i < nb; i += 256) {
        s  += base[((size_t)i * cout + co) * 2];
        ss += base[((size_t)i * cout + co) * 2 + 1];
    }
#pragma unroll
    for (int o = 32; o > 0; o >>= 1) {
        s += __shfl_down(s, o);
        ss += __shfl_down(ss, o);
    }
    __shared__ float ls[4], lss[4];
    int w = threadIdx.x >> 6;
    if ((threadIdx.x & 63) == 0) { ls[w] = s; lss[w] = ss; }
    __syncthreads();
    if (threadIdx.x == 0) {
        sums[c * 2]     = ls[0] + ls[1] + ls[2] + ls[3];
        sums[c * 2 + 1] = lss[0] + lss[1] + lss[2] + lss[3];
    }
}

// ---- LSTM elementwise ----
__global__ __launch_bounds__(256) void lstm_elem_kernel(
    const float* __restrict__ gates, const float* __restrict__ S,
    const float* __restrict__ prev_c, float* __restrict__ out)
{
    __shared__ float mn[128], is_[128];
    int tid = threadIdx.x;
    if (tid < 128) {
        float s = S[tid * 2], ss = S[tid * 2 + 1];
        float m = s * (1.f / HW_);
        mn[tid] = m;
        is_[tid] = rsqrtf(ss * (1.f / HW_) - m * m + EPS_);
    }
    __syncthreads();
    size_t p = (size_t)(blockIdx.x * 256 + tid) * 4;
    for (int ch = 0; ch < 32; ++ch) {
        f4 fv = *(const f4*)(gates + (size_t)ch * HW_ + p);
        f4 iv = *(const f4*)(gates + (size_t)(32 + ch) * HW_ + p);
        f4 cv = *(const f4*)(gates + (size_t)(64 + ch) * HW_ + p);
        f4 ov = *(const f4*)(gates + (size_t)(96 + ch) * HW_ + p);
        f4 pc = *(const f4*)(prev_c + (size_t)ch * HW_ + p);
        float fm = mn[ch], fs = is_[ch];
        float im = mn[32 + ch], isd = is_[32 + ch];
        float cm = mn[64 + ch], cs = is_[64 + ch];
        float om = mn[96 + ch], os = is_[96 + ch];
        f4 nc, nh;
#pragma unroll
        for (int k = 0; k < 4; ++k) {
            float f = sigmoidf_((fv[k] - fm) * fs);
            float i = sigmoidf_((iv[k] - im) * isd);
            float c = tanhf((cv[k] - cm) * cs);
            float o = sigmoidf_((ov[k] - om) * os);
            float ncv = pc[k] * f + i * c;
            nc[k] = ncv;
            nh[k] = tanhf(ncv) * o;
        }
        *(f4*)(out + (size_t)ch * HW_ + p) = nc;
        *(f4*)(out + (size_t)32 * HW_ + (size_t)ch * HW_ + p) = nh;
    }
}

// ---- hole gather ----
__global__ void holes_kernel(const float* __restrict__ rm, const float* __restrict__ S,
                             const int* __restrict__ holes,
                             const float* __restrict__ w_oil, const float* __restrict__ b_oil,
                             const float* __restrict__ w_wat, const float* __restrict__ b_wat,
                             const float* __restrict__ w_gas, const float* __restrict__ b_gas,
                             float* __restrict__ res)
{
    int i = threadIdx.x;
    int hx = holes[i * 2], hy = holes[i * 2 + 1];
    const float invn = 1.f / (float)RMHW;
#pragma unroll
    for (int c = 0; c < 3; ++c) {
        float s = S[c * 2], ss = S[c * 2 + 1];
        float m = s * invn;
        float istd = rsqrtf(ss * invn - m * m + EPS_);
        float raw = rm[(size_t)c * RMHW + (size_t)(hx + 3) * RMH + (hy + 3)];
        float nv = (raw - m) * istd;
        float w = (c == 0) ? w_oil[0] : (c == 1) ? w_wat[0] : w_gas[0];
        float b = (c == 0) ? b_oil[0] : (c == 1) ? b_wat[0] : b_gas[0];
        res[i * 3 + c] = nv * w + b;
    }
}

extern "C" void kernel_launch(void* const* d_in, const int* in_sizes, int n_in,
                              void* d_out, int out_size, void* d_ws, size_t ws_size,
                              hipStream_t stream) {
    const float* x      = (const float*)d_in[0];
    const float* prev_c = (const float*)d_in[1];
    const float* prev_h = (const float*)d_in[2];
    const int*   holes  = (const int*)d_in[3];
    const float* w_e1 = (const float*)d_in[4];
    const float* w_e2 = (const float*)d_in[5];
    const float* w_f  = (const float*)d_in[6];
    const float* w_i  = (const float*)d_in[7];
    const float* w_c  = (const float*)d_in[8];
    const float* w_o  = (const float*)d_in[9];
    const float* w_r1 = (const float*)d_in[10];
    const float* w_r2 = (const float*)d_in[11];
    const float* w_oil = (const float*)d_in[12];
    const float* b_oil = (const float*)d_in[13];
    const float* w_wat = (const float*)d_in[14];
    const float* b_wat = (const float*)d_in[15];
    const float* w_gas = (const float*)d_in[16];
    const float* b_gas = (const float*)d_in[17];

    float* out = (float*)d_out;
    float* ws  = (float*)d_ws;

    size_t o = 0;
    float* wt_e1 = ws + o; o += 4 * 9 * 32;
    float* wt_e2 = ws + o; o += 32 * 9 * 32;
    float* wt_g  = ws + o; o += 4 * 64 * 9 * 32;
    float* wt_r1 = ws + o; o += 32 * 9 * 32;
    float* wt_r2 = ws + o; o += 32 * 9 * 3;
    float* gbias = ws + o; o += 128;
    float* y1    = ws + o; o += (size_t)32 * HW_;   // reused as r1
    float* y2    = ws + o; o += (size_t)32 * HW_;   // reused as rm
    float* gates = ws + o; o += (size_t)128 * HW_;
    float* P1 = ws + o; o += 1024 * 32 * 2;
    float* P2 = ws + o; o += 1024 * 32 * 2;
    float* P3 = ws + o; o += 4096 * 32 * 2;
    float* P4 = ws + o; o += 1024 * 32 * 2;
    float* P5 = ws + o; o += 1089 * 3 * 2;
    float* S1 = ws + o; o += 64;
    float* S2 = ws + o; o += 64;
    float* S3 = ws + o; o += 256;
    float* S4 = ws + o; o += 64;
    float* S5 = ws + o; o += 8;
    float* r1 = y1;
    float* rm = y2;

    const float invHW = 1.f / (float)HW_;
    dim3 blk(256);

    wtrans_kernel<<<dim3(5), blk, 0, stream>>>(w_e1, wt_e1, 4, 32);
    wtrans_kernel<<<dim3(36), blk, 0, stream>>>(w_e2, wt_e2, 32, 32);
    wtrans_kernel<<<dim3(72), blk, 0, stream>>>(w_f, wt_g + 0 * 64 * 9 * 32, 64, 32);
    wtrans_kernel<<<dim3(72), blk, 0, stream>>>(w_i, wt_g + 1 * 64 * 9 * 32, 64, 32);
    wtrans_kernel<<<dim3(72), blk, 0, stream>>>(w_c, wt_g + 2 * 64 * 9 * 32, 64, 32);
    wtrans_kernel<<<dim3(72), blk, 0, stream>>>(w_o, wt_g + 3 * 64 * 9 * 32, 64, 32);
    wtrans_kernel<<<dim3(36), blk, 0, stream>>>(w_r1, wt_r1, 32, 32);
    wtrans_kernel<<<dim3(4),  blk, 0, stream>>>(w_r2, wt_r2, 32, 3);

    // conv_e1: x(4ch) raw -> y1 + P1
    conv3x3_kernel<4, 32, 1, 0><<<dim3(32, 32), blk, 0, stream>>>(
        x, nullptr, wt_e1, y1, P1, H_, W_, invHW);
    reduce_kernel<<<dim3(32), blk, 0, stream>>>(P1, S1, 1024, 32);

    // conv_e2: norm+relu(y1) -> y2 + P2
    conv3x3_kernel<32, 32, 1, 2><<<dim3(32, 32), blk, 0, stream>>>(
        y1, S1, wt_e2, y2, P2, H_, W_, invHW);
    reduce_kernel<<<dim3(32), blk, 0, stream>>>(P2, S2, 1024, 32);

    // fold BN(y2) into gate weights, then fused 4-gate conv on raw inputs
    wgprep_kernel<<<dim3(1), dim3(128), 0, stream>>>(wt_g, S2, gbias);
    conv_gates_kernel<<<dim3(32, 32), dim3(1024), 0, stream>>>(
        prev_h, y2, S2, wt_g, gbias, gates, P3);
    reduce_kernel<<<dim3(128), blk, 0, stream>>>(P3, S3, 1024, 32);

    lstm_elem_kernel<<<dim3(256), blk, 0, stream>>>(gates, S3, prev_c, out);

    // conv_r1: next_h raw -> r1 + P4
    conv3x3_kernel<32, 32, 1, 0><<<dim3(32, 32), blk, 0, stream>>>(
        out + (size_t)32 * HW_, nullptr, wt_r1, r1, P4, H_, W_, invHW);
    reduce_kernel<<<dim3(32), blk, 0, stream>>>(P4, S4, 1024, 32);

    // conv_r2: norm+relu(r1), pad=4 -> rm (3 x 518 x 518) + P5
    conv3x3_kernel<32, 3, 4, 2><<<dim3(33, 33), blk, 0, stream>>>(
        r1, S4, wt_r2, rm, P5, RMH, RMH, invHW);
    reduce_kernel<<<dim3(3), blk, 0, stream>>>(P5, S5, 1089, 3);

    holes_kernel<<<dim3(1), blk, 0, stream>>>(
        rm, S5, holes, w_oil, b_oil, w_wat, b_wat, w_gas, b_gas,
        out + (size_t)64 * HW_);
}

// Round 3
// 6756.096 us; speedup vs baseline: 6.1538x; 6.1538x over previous
//
#include <hip/hip_runtime.h>
#include <cstddef>

// ConvLSTM cell, fp32 direct conv, BN-stat fusion, reg-staged LDS double-buffer.
// Gate conv: 256-thread blocks, 2 gates per block (acc[2][32]), BN of x_emb folded
// into pre-scaled weights + bias (pad = mean trick). 256 threads keeps VGPR budget
// at 512/4-waves -> no spills (the 1024-thread variant spilled: 79 GB scratch writes).

typedef float f4 __attribute__((ext_vector_type(4)));

#define H_   512
#define W_   512
#define HW_  (H_ * W_)
#define EPS_ 1e-5f
#define RMH  518
#define RMHW (RMH * RMH)
#define TS   16

static __device__ __forceinline__ float sigmoidf_(float x) { return 1.f / (1.f + expf(-x)); }

// ---- weight transpose: [COUT][CIN][3][3] -> [CIN*9][COUT] ----
__global__ void wtrans_kernel(const float* __restrict__ src, float* __restrict__ dst,
                              int cin, int cout) {
    int n = cout * cin * 9;
    int idx = blockIdx.x * 256 + threadIdx.x;
    if (idx < n) {
        int co = idx / (cin * 9);
        int r  = idx - co * cin * 9;
        dst[r * cout + co] = src[idx];
    }
}

// ---- fold BN(x_emb) into gate weights (in place) + bias; 128 threads = (z,co) ----
__global__ void wgprep_kernel(float* __restrict__ wt, const float* __restrict__ S2,
                              float* __restrict__ bias) {
    int tid = threadIdx.x;
    int z = tid >> 5, co = tid & 31;
    __shared__ float m_[32], is_[32];
    if (tid < 32) {
        float s = S2[tid * 2], ss = S2[tid * 2 + 1];
        float m = s * (1.f / HW_);
        m_[tid] = m;
        is_[tid] = rsqrtf(ss * (1.f / HW_) - m * m + EPS_);
    }
    __syncthreads();
    float b = 0.f;
    float* wz = wt + (size_t)z * 64 * 9 * 32;
    for (int ci = 32; ci < 64; ++ci) {
        float m = m_[ci - 32], is = is_[ci - 32];
        for (int k = 0; k < 9; ++k) {
            size_t idx = (size_t)(ci * 9 + k) * 32 + co;
            float w = wz[idx] * is;
            wz[idx] = w;
            b -= m * w;   // cancels the pad=mean substitution at borders
        }
    }
    bias[tid] = b;
}

// ---- generic direct 3x3 conv, 16x16 tile, reg-staged LDS dbuf ----
// MODE: 0 = raw input; 2 = BN-normalize + relu at LDS-write time.
template <int CIN, int COUT, int PAD, int MODE>
__global__ __launch_bounds__(256) void conv3x3_kernel(
    const float* __restrict__ in, const float* __restrict__ sums,
    const float* __restrict__ wt, float* __restrict__ out,
    float* __restrict__ partials, int OH, int OW, float inv_n_in)
{
    constexpr int CH   = (CIN < 8) ? CIN : 8;
    constexpr int NCH  = CIN / CH;
    constexpr int NB   = (NCH > 1) ? 2 : 1;
    constexpr int NELE = CH * 324;
    constexpr int NREG = (NELE + 255) / 256;
    constexpr int NCA  = (MODE == 2) ? CIN : 1;

    __shared__ float smem[NB][NELE];
    __shared__ float s_mean[NCA], s_istd[NCA];
    __shared__ float red[4][COUT][2];

    const int tid = threadIdx.x;
    const int tx = tid & 15, ty = tid >> 4;
    const int bx = blockIdx.x, by = blockIdx.y;

    if constexpr (MODE == 2) {
        if (tid < CIN) {
            float s = sums[tid * 2], ss = sums[tid * 2 + 1];
            float m = s * inv_n_in;
            s_mean[tid] = m;
            s_istd[tid] = rsqrtf(ss * inv_n_in - m * m + EPS_);
        }
        __syncthreads();
    }

    float stg[NREG];

    auto load_chunk = [&](int cc) {
#pragma unroll
        for (int r = 0; r < NREG; ++r) {
            int i = tid + r * 256;
            if (i < NELE) {
                int ci = i / 324;
                int rem = i - ci * 324;
                int ly = rem / 18, lx = rem - ly * 18;
                int gy = by * TS + ly - PAD, gx = bx * TS + lx - PAD;
                int c = cc * CH + ci;
                float v;
                if ((unsigned)gy < 512u && (unsigned)gx < 512u)
                    v = in[(size_t)c * HW_ + gy * 512 + gx];
                else
                    v = (MODE == 2) ? s_mean[c] : 0.f;  // pad: mean -> normalizes to 0
                stg[r] = v;
            }
        }
    };
    auto write_chunk = [&](int cc, int buf) {
#pragma unroll
        for (int r = 0; r < NREG; ++r) {
            int i = tid + r * 256;
            if (i < NELE) {
                float v = stg[r];
                if constexpr (MODE == 2) {
                    int ci = i / 324;
                    int c = cc * CH + ci;
                    v = fmaxf((v - s_mean[c]) * s_istd[c], 0.f);
                }
                smem[buf][i] = v;
            }
        }
    };

    float acc[COUT];
#pragma unroll
    for (int i = 0; i < COUT; ++i) acc[i] = 0.f;

    load_chunk(0);
    write_chunk(0, 0);
    __syncthreads();

#pragma unroll 1
    for (int cc = 0; cc < NCH; ++cc) {
        if (cc + 1 < NCH) load_chunk(cc + 1);          // issue early: latency under compute
        const float* sp = smem[(NB == 1) ? 0 : (cc & 1)];
        const float* wc = wt + (size_t)cc * CH * 9 * COUT;
#pragma unroll
        for (int ci = 0; ci < CH; ++ci) {
#pragma unroll
            for (int kk = 0; kk < 9; ++kk) {
                const int ky = kk / 3, kx = kk - ky * 3;
                float v = sp[ci * 324 + (ty + ky) * 18 + (tx + kx)];
                const float* w = wc + (ci * 9 + kk) * COUT;
#pragma unroll
                for (int co = 0; co < COUT; ++co)
                    acc[co] = fmaf(v, w[co], acc[co]);
            }
        }
        if (cc + 1 < NCH) write_chunk(cc + 1, 1 - (cc & 1));
        __syncthreads();
    }

    const int oy = by * TS + ty, ox = bx * TS + tx;
    const bool valid = (oy < OH) && (ox < OW);
    if (valid) {
#pragma unroll
        for (int co = 0; co < COUT; ++co)
            out[(size_t)co * OH * OW + oy * OW + ox] = acc[co];
    }

    const float scale = valid ? 1.f : 0.f;
    const int wave = tid >> 6, lane = tid & 63;
#pragma unroll
    for (int co = 0; co < COUT; ++co) {
        float s = acc[co] * scale;
        float ss = acc[co] * acc[co] * scale;
#pragma unroll
        for (int o = 32; o > 0; o >>= 1) {
            s += __shfl_down(s, o);
            ss += __shfl_down(ss, o);
        }
        if (lane == 0) { red[wave][co][0] = s; red[wave][co][1] = ss; }
    }
    __syncthreads();
    if (tid < COUT) {
        float s = red[0][tid][0] + red[1][tid][0] + red[2][tid][0] + red[3][tid][0];
        float ss = red[0][tid][1] + red[1][tid][1] + red[2][tid][1] + red[3][tid][1];
        int bl = by * gridDim.x + bx;
        partials[((size_t)bl * COUT + tid) * 2]     = s;
        partials[((size_t)bl * COUT + tid) * 2 + 1] = ss;
    }
}

// ---- fused gate conv: 256 threads, 2 gates per block (grid.z = 2) ----
// Inputs raw (prev_h pad 0; y2 pad mean via s_pad), weights pre-folded (wgprep).
__global__ __launch_bounds__(256) void conv_gates_kernel(
    const float* __restrict__ ph, const float* __restrict__ y2,
    const float* __restrict__ S2, const float* __restrict__ wt,
    const float* __restrict__ bias, float* __restrict__ out,
    float* __restrict__ partials)
{
    __shared__ float smem[2][2592];      // 8ch x 18x18, double-buffered
    __shared__ float s_pad[64];          // border fill: 0 for prev_h, mean2 for x_emb
    __shared__ float red[4][2][32][2];

    const int tid = threadIdx.x;
    const int tx = tid & 15, ty = tid >> 4;
    const int bx = blockIdx.x, by = blockIdx.y, z = blockIdx.z;   // z in {0,1}

    if (tid < 64) {
        float pv = 0.f;
        if (tid >= 32) pv = S2[(tid - 32) * 2] * (1.f / HW_);
        s_pad[tid] = pv;
    }
    __syncthreads();   // s_pad ready before first load_chunk

    float stg[11];

    auto load_chunk = [&](int cc) {
#pragma unroll
        for (int r = 0; r < 11; ++r) {
            int i = tid + r * 256;
            if (i < 2592) {
                int ci = i / 324;
                int rem = i - ci * 324;
                int ly = rem / 18, lx = rem - ly * 18;
                int gy = by * TS + ly - 1, gx = bx * TS + lx - 1;
                int c = cc * 8 + ci;
                float v;
                if ((unsigned)gy < 512u && (unsigned)gx < 512u) {
                    const float* src = (c < 32) ? (ph + (size_t)c * HW_)
                                                : (y2 + (size_t)(c - 32) * HW_);
                    v = src[gy * 512 + gx];
                } else {
                    v = s_pad[c];
                }
                stg[r] = v;
            }
        }
    };
    auto write_chunk = [&](int buf) {
#pragma unroll
        for (int r = 0; r < 11; ++r) {
            int i = tid + r * 256;
            if (i < 2592) smem[buf][i] = stg[r];
        }
    };

    float acc0[32], acc1[32];
#pragma unroll
    for (int co = 0; co < 32; ++co) {
        acc0[co] = bias[(2 * z) * 32 + co];
        acc1[co] = bias[(2 * z + 1) * 32 + co];
    }

    load_chunk(0);
    write_chunk(0);
    __syncthreads();

    const float* wz0 = wt + (size_t)(2 * z) * 64 * 9 * 32;
    const float* wz1 = wz0 + 64 * 9 * 32;

#pragma unroll 1
    for (int cc = 0; cc < 8; ++cc) {
        if (cc < 7) load_chunk(cc + 1);       // issue loads early: latency under compute
        const float* sp = smem[cc & 1];
        const float* w0c = wz0 + cc * 8 * 9 * 32;
        const float* w1c = wz1 + cc * 8 * 9 * 32;
#pragma unroll
        for (int ci = 0; ci < 8; ++ci) {
#pragma unroll
            for (int kk = 0; kk < 9; ++kk) {
                const int ky = kk / 3, kx = kk - ky * 3;
                float v = sp[ci * 324 + (ty + ky) * 18 + (tx + kx)];
                const float* wa = w0c + (ci * 9 + kk) * 32;
                const float* wb = w1c + (ci * 9 + kk) * 32;
#pragma unroll
                for (int co = 0; co < 32; ++co) {
                    acc0[co] = fmaf(v, wa[co], acc0[co]);
                    acc1[co] = fmaf(v, wb[co], acc1[co]);
                }
            }
        }
        if (cc < 7) write_chunk(1 - (cc & 1));
        __syncthreads();
    }

    const int oy = by * TS + ty, ox = bx * TS + tx;
    const size_t p = (size_t)oy * 512 + ox;
    float* o0 = out + (size_t)(2 * z) * 32 * HW_;
    float* o1 = out + (size_t)(2 * z + 1) * 32 * HW_;
#pragma unroll
    for (int co = 0; co < 32; ++co) {
        o0[(size_t)co * HW_ + p] = acc0[co];
        o1[(size_t)co * HW_ + p] = acc1[co];
    }

    const int wave = tid >> 6, lane = tid & 63;
#pragma unroll
    for (int co = 0; co < 32; ++co) {
        float s0 = acc0[co], ss0 = acc0[co] * acc0[co];
        float s1 = acc1[co], ss1 = acc1[co] * acc1[co];
#pragma unroll
        for (int o = 32; o > 0; o >>= 1) {
            s0 += __shfl_down(s0, o);  ss0 += __shfl_down(ss0, o);
            s1 += __shfl_down(s1, o);  ss1 += __shfl_down(ss1, o);
        }
        if (lane == 0) {
            red[wave][0][co][0] = s0;  red[wave][0][co][1] = ss0;
            red[wave][1][co][0] = s1;  red[wave][1][co][1] = ss1;
        }
    }
    __syncthreads();
    if (tid < 64) {
        int gi = tid >> 5, co = tid & 31;
        float s = 0.f, ss = 0.f;
#pragma unroll
        for (int w = 0; w < 4; ++w) {
            s  += red[w][gi][co][0];
            ss += red[w][gi][co][1];
        }
        int bl = (2 * z + gi) * 1024 + by * 32 + bx;
        partials[((size_t)bl * 32 + co) * 2]     = s;
        partials[((size_t)bl * 32 + co) * 2 + 1] = ss;
    }
}

// ---- reduce per-block partials -> per-channel (sum, sumsq) ----
__global__ __launch_bounds__(256) void reduce_kernel(const float* __restrict__ p,
                                                     float* __restrict__ sums,
                                                     int nb, int cout) {
    int c = blockIdx.x;
    int g = c / cout, co = c - g * cout;
    const float* base = p + (size_t)g * nb * cout * 2;
    float s = 0.f, ss = 0.f;
    for (int i = threadIdx.x; i < nb; i += 256) {
        s  += base[((size_t)i * cout + co) * 2];
        ss += base[((size_t)i * cout + co) * 2 + 1];
    }
#pragma unroll
    for (int o = 32; o > 0; o >>= 1) {
        s += __shfl_down(s, o);
        ss += __shfl_down(ss, o);
    }
    __shared__ float ls[4], lss[4];
    int w = threadIdx.x >> 6;
    if ((threadIdx.x & 63) == 0) { ls[w] = s; lss[w] = ss; }
    __syncthreads();
    if (threadIdx.x == 0) {
        sums[c * 2]     = ls[0] + ls[1] + ls[2] + ls[3];
        sums[c * 2 + 1] = lss[0] + lss[1] + lss[2] + lss[3];
    }
}

// ---- LSTM elementwise ----
__global__ __launch_bounds__(256) void lstm_elem_kernel(
    const float* __restrict__ gates, const float* __restrict__ S,
    const float* __restrict__ prev_c, float* __restrict__ out)
{
    __shared__ float mn[128], is_[128];
    int tid = threadIdx.x;
    if (tid < 128) {
        float s = S[tid * 2], ss = S[tid * 2 + 1];
        float m = s * (1.f / HW_);
        mn[tid] = m;
        is_[tid] = rsqrtf(ss * (1.f / HW_) - m * m + EPS_);
    }
    __syncthreads();
    size_t p = (size_t)(blockIdx.x * 256 + tid) * 4;
    for (int ch = 0; ch < 32; ++ch) {
        f4 fv = *(const f4*)(gates + (size_t)ch * HW_ + p);
        f4 iv = *(const f4*)(gates + (size_t)(32 + ch) * HW_ + p);
        f4 cv = *(const f4*)(gates + (size_t)(64 + ch) * HW_ + p);
        f4 ov = *(const f4*)(gates + (size_t)(96 + ch) * HW_ + p);
        f4 pc = *(const f4*)(prev_c + (size_t)ch * HW_ + p);
        float fm = mn[ch], fs = is_[ch];
        float im = mn[32 + ch], isd = is_[32 + ch];
        float cm = mn[64 + ch], cs = is_[64 + ch];
        float om = mn[96 + ch], os = is_[96 + ch];
        f4 nc, nh;
#pragma unroll
        for (int k = 0; k < 4; ++k) {
            float f = sigmoidf_((fv[k] - fm) * fs);
            float i = sigmoidf_((iv[k] - im) * isd);
            float c = tanhf((cv[k] - cm) * cs);
            float o = sigmoidf_((ov[k] - om) * os);
            float ncv = pc[k] * f + i * c;
            nc[k] = ncv;
            nh[k] = tanhf(ncv) * o;
        }
        *(f4*)(out + (size_t)ch * HW_ + p) = nc;
        *(f4*)(out + (size_t)32 * HW_ + (size_t)ch * HW_ + p) = nh;
    }
}

// ---- hole gather ----
__global__ void holes_kernel(const float* __restrict__ rm, const float* __restrict__ S,
                             const int* __restrict__ holes,
                             const float* __restrict__ w_oil, const float* __restrict__ b_oil,
                             const float* __restrict__ w_wat, const float* __restrict__ b_wat,
                             const float* __restrict__ w_gas, const float* __restrict__ b_gas,
                             float* __restrict__ res)
{
    int i = threadIdx.x;
    int hx = holes[i * 2], hy = holes[i * 2 + 1];
    const float invn = 1.f / (float)RMHW;
#pragma unroll
    for (int c = 0; c < 3; ++c) {
        float s = S[c * 2], ss = S[c * 2 + 1];
        float m = s * invn;
        float istd = rsqrtf(ss * invn - m * m + EPS_);
        float raw = rm[(size_t)c * RMHW + (size_t)(hx + 3) * RMH + (hy + 3)];
        float nv = (raw - m) * istd;
        float w = (c == 0) ? w_oil[0] : (c == 1) ? w_wat[0] : w_gas[0];
        float b = (c == 0) ? b_oil[0] : (c == 1) ? b_wat[0] : b_gas[0];
        res[i * 3 + c] = nv * w + b;
    }
}

extern "C" void kernel_launch(void* const* d_in, const int* in_sizes, int n_in,
                              void* d_out, int out_size, void* d_ws, size_t ws_size,
                              hipStream_t stream) {
    const float* x      = (const float*)d_in[0];
    const float* prev_c = (const float*)d_in[1];
    const float* prev_h = (const float*)d_in[2];
    const int*   holes  = (const int*)d_in[3];
    const float* w_e1 = (const float*)d_in[4];
    const float* w_e2 = (const float*)d_in[5];
    const float* w_f  = (const float*)d_in[6];
    const float* w_i  = (const float*)d_in[7];
    const float* w_c  = (const float*)d_in[8];
    const float* w_o  = (const float*)d_in[9];
    const float* w_r1 = (const float*)d_in[10];
    const float* w_r2 = (const float*)d_in[11];
    const float* w_oil = (const float*)d_in[12];
    const float* b_oil = (const float*)d_in[13];
    const float* w_wat = (const float*)d_in[14];
    const float* b_wat = (const float*)d_in[15];
    const float* w_gas = (const float*)d_in[16];
    const float* b_gas = (const float*)d_in[17];

    float* out = (float*)d_out;
    float* ws  = (float*)d_ws;

    size_t o = 0;
    float* wt_e1 = ws + o; o += 4 * 9 * 32;
    float* wt_e2 = ws + o; o += 32 * 9 * 32;
    float* wt_g  = ws + o; o += 4 * 64 * 9 * 32;
    float* wt_r1 = ws + o; o += 32 * 9 * 32;
    float* wt_r2 = ws + o; o += 32 * 9 * 3;
    float* gbias = ws + o; o += 128;
    float* y1    = ws + o; o += (size_t)32 * HW_;   // reused as r1
    float* y2    = ws + o; o += (size_t)32 * HW_;   // reused as rm
    float* gates = ws + o; o += (size_t)128 * HW_;
    float* P1 = ws + o; o += 1024 * 32 * 2;
    float* P2 = ws + o; o += 1024 * 32 * 2;
    float* P3 = ws + o; o += 4096 * 32 * 2;
    float* P4 = ws + o; o += 1024 * 32 * 2;
    float* P5 = ws + o; o += 1089 * 3 * 2;
    float* S1 = ws + o; o += 64;
    float* S2 = ws + o; o += 64;
    float* S3 = ws + o; o += 256;
    float* S4 = ws + o; o += 64;
    float* S5 = ws + o; o += 8;
    float* r1 = y1;
    float* rm = y2;

    const float invHW = 1.f / (float)HW_;
    dim3 blk(256);

    wtrans_kernel<<<dim3(5), blk, 0, stream>>>(w_e1, wt_e1, 4, 32);
    wtrans_kernel<<<dim3(36), blk, 0, stream>>>(w_e2, wt_e2, 32, 32);
    wtrans_kernel<<<dim3(72), blk, 0, stream>>>(w_f, wt_g + 0 * 64 * 9 * 32, 64, 32);
    wtrans_kernel<<<dim3(72), blk, 0, stream>>>(w_i, wt_g + 1 * 64 * 9 * 32, 64, 32);
    wtrans_kernel<<<dim3(72), blk, 0, stream>>>(w_c, wt_g + 2 * 64 * 9 * 32, 64, 32);
    wtrans_kernel<<<dim3(72), blk, 0, stream>>>(w_o, wt_g + 3 * 64 * 9 * 32, 64, 32);
    wtrans_kernel<<<dim3(36), blk, 0, stream>>>(w_r1, wt_r1, 32, 32);
    wtrans_kernel<<<dim3(4),  blk, 0, stream>>>(w_r2, wt_r2, 32, 3);

    // conv_e1: x(4ch) raw -> y1 + P1
    conv3x3_kernel<4, 32, 1, 0><<<dim3(32, 32), blk, 0, stream>>>(
        x, nullptr, wt_e1, y1, P1, H_, W_, invHW);
    reduce_kernel<<<dim3(32), blk, 0, stream>>>(P1, S1, 1024, 32);

    // conv_e2: norm+relu(y1) -> y2 + P2
    conv3x3_kernel<32, 32, 1, 2><<<dim3(32, 32), blk, 0, stream>>>(
        y1, S1, wt_e2, y2, P2, H_, W_, invHW);
    reduce_kernel<<<dim3(32), blk, 0, stream>>>(P2, S2, 1024, 32);

    // fold BN(y2) into gate weights, then fused 2-gates-per-block conv on raw inputs
    wgprep_kernel<<<dim3(1), dim3(128), 0, stream>>>(wt_g, S2, gbias);
    conv_gates_kernel<<<dim3(32, 32, 2), blk, 0, stream>>>(
        prev_h, y2, S2, wt_g, gbias, gates, P3);
    reduce_kernel<<<dim3(128), blk, 0, stream>>>(P3, S3, 1024, 32);

    lstm_elem_kernel<<<dim3(256), blk, 0, stream>>>(gates, S3, prev_c, out);

    // conv_r1: next_h raw -> r1 + P4
    conv3x3_kernel<32, 32, 1, 0><<<dim3(32, 32), blk, 0, stream>>>(
        out + (size_t)32 * HW_, nullptr, wt_r1, r1, P4, H_, W_, invHW);
    reduce_kernel<<<dim3(32), blk, 0, stream>>>(P4, S4, 1024, 32);

    // conv_r2: norm+relu(r1), pad=4 -> rm (3 x 518 x 518) + P5
    conv3x3_kernel<32, 3, 4, 2><<<dim3(33, 33), blk, 0, stream>>>(
        r1, S4, wt_r2, rm, P5, RMH, RMH, invHW);
    reduce_kernel<<<dim3(3), blk, 0, stream>>>(P5, S5, 1089, 3);

    holes_kernel<<<dim3(1), blk, 0, stream>>>(
        rm, S5, holes, w_oil, b_oil, w_wat, b_wat, w_gas, b_gas,
        out + (size_t)64 * HW_);
}

// Round 4
// 4337.508 us; speedup vs baseline: 9.5851x; 1.5576x over previous
//
#include <hip/hip_runtime.h>
#include <cstddef>

// ConvLSTM cell, fp32 direct conv. R4: single-weight-stream blocks everywhere
// (keeps weight loads in SGPRs — the 2-stream R3 variant demoted them to per-lane
// vector loads, +97 VALU/iter, 8x slowdown), reg-staged LDS double-buffer with
// hoisted fill addressing, BN of x_emb folded into gate weights (pad=mean trick).

typedef float f4 __attribute__((ext_vector_type(4)));

#define H_   512
#define W_   512
#define HW_  (H_ * W_)
#define EPS_ 1e-5f
#define RMH  518
#define RMHW (RMH * RMH)
#define TS   16

static __device__ __forceinline__ float sigmoidf_(float x) { return 1.f / (1.f + expf(-x)); }

// ---- weight transpose: [COUT][CIN][3][3] -> [CIN*9][COUT] ----
__global__ void wtrans_kernel(const float* __restrict__ src, float* __restrict__ dst,
                              int cin, int cout) {
    int n = cout * cin * 9;
    int idx = blockIdx.x * 256 + threadIdx.x;
    if (idx < n) {
        int co = idx / (cin * 9);
        int r  = idx - co * cin * 9;
        dst[r * cout + co] = src[idx];
    }
}

// ---- fold BN(x_emb) into gate weights (in place) + bias; 128 threads = (z,co) ----
__global__ void wgprep_kernel(float* __restrict__ wt, const float* __restrict__ S2,
                              float* __restrict__ bias) {
    int tid = threadIdx.x;
    int z = tid >> 5, co = tid & 31;
    __shared__ float m_[32], is_[32];
    if (tid < 32) {
        float s = S2[tid * 2], ss = S2[tid * 2 + 1];
        float m = s * (1.f / HW_);
        m_[tid] = m;
        is_[tid] = rsqrtf(ss * (1.f / HW_) - m * m + EPS_);
    }
    __syncthreads();
    float b = 0.f;
    float* wz = wt + (size_t)z * 64 * 9 * 32;
    for (int ci = 32; ci < 64; ++ci) {
        float m = m_[ci - 32], is = is_[ci - 32];
        for (int k = 0; k < 9; ++k) {
            size_t idx = (size_t)(ci * 9 + k) * 32 + co;
            float w = wz[idx] * is;
            wz[idx] = w;
            b -= m * w;   // cancels the pad=mean substitution at borders
        }
    }
    bias[tid] = b;
}

// ---- generic direct 3x3 conv, 16x16 tile, reg-staged dbuf, hoisted addressing ----
// MODE: 0 = raw input (pad 0); 2 = BN-normalize + relu at LDS-write time (pad -> 0).
template <int CIN, int COUT, int PAD, int MODE>
__global__ __launch_bounds__(256) void conv3x3_kernel(
    const float* __restrict__ in, const float* __restrict__ sums,
    const float* __restrict__ wt, float* __restrict__ out,
    float* __restrict__ partials, int OH, int OW, float inv_n_in)
{
    constexpr int CH      = (CIN < 8) ? CIN : 8;
    constexpr int NCH     = CIN / CH;
    constexpr int NB      = (NCH > 1) ? 2 : 1;
    constexpr int NELE    = CH * 324;
    constexpr int NREG    = (NELE + 255) / 256;
    constexpr int CSTRIDE = CH * HW_;
    constexpr int NCA     = (MODE == 2) ? CIN : 1;

    __shared__ float smem[NB][NELE];
    __shared__ float s_mean[NCA], s_istd[NCA];
    __shared__ float red[4][COUT][2];

    const int tid = threadIdx.x;
    const int tx = tid & 15, ty = tid >> 4;
    const int bx = blockIdx.x, by = blockIdx.y;

    if constexpr (MODE == 2) {
        if (tid < CIN) {
            float s = sums[tid * 2], ss = sums[tid * 2 + 1];
            float m = s * inv_n_in;
            s_mean[tid] = m;
            s_istd[tid] = rsqrtf(ss * inv_n_in - m * m + EPS_);
        }
        __syncthreads();   // s_mean/s_istd ready before first write_chunk
    }

    // hoisted fill addressing: goff>=0 valid, -1 pad, -2 no element
    int goff[NREG], cidx[NREG];
#pragma unroll
    for (int r = 0; r < NREG; ++r) {
        int i = tid + r * 256;
        if (i < NELE) {
            int ci = i / 324;
            int rem = i - ci * 324;
            int ly = rem / 18, lx = rem - ly * 18;
            int gy = by * TS + ly - PAD, gx = bx * TS + lx - PAD;
            bool ok = ((unsigned)gy < 512u) && ((unsigned)gx < 512u);
            goff[r] = ok ? (ci * HW_ + gy * 512 + gx) : -1;
            cidx[r] = ci;
        } else { goff[r] = -2; cidx[r] = 0; }
    }

    float stg[NREG];
    auto load_chunk = [&](int cc) {
#pragma unroll
        for (int r = 0; r < NREG; ++r)
            if (goff[r] >= 0) stg[r] = in[(size_t)goff[r] + (size_t)cc * CSTRIDE];
    };
    auto write_chunk = [&](int cc, int buf) {
#pragma unroll
        for (int r = 0; r < NREG; ++r) {
            if (goff[r] != -2) {
                float v = 0.f;
                if (goff[r] >= 0) {
                    v = stg[r];
                    if constexpr (MODE == 2) {
                        int c = cc * CH + cidx[r];
                        v = fmaxf((v - s_mean[c]) * s_istd[c], 0.f);
                    }
                }
                smem[buf][tid + r * 256] = v;
            }
        }
    };

    float acc[COUT];
#pragma unroll
    for (int i = 0; i < COUT; ++i) acc[i] = 0.f;

    load_chunk(0);
    write_chunk(0, 0);
    __syncthreads();

#pragma unroll 1
    for (int cc = 0; cc < NCH; ++cc) {
        if (cc + 1 < NCH) load_chunk(cc + 1);     // issue early: latency under compute
        const float* sp = smem[(NB == 1) ? 0 : (cc & 1)];
        const float* wc = wt + (size_t)cc * CH * 9 * COUT;
#pragma unroll
        for (int ci = 0; ci < CH; ++ci) {
#pragma unroll
            for (int kk = 0; kk < 9; ++kk) {
                const int ky = kk / 3, kx = kk - ky * 3;
                float v = sp[ci * 324 + (ty + ky) * 18 + (tx + kx)];
                const float* w = wc + (ci * 9 + kk) * COUT;
#pragma unroll
                for (int co = 0; co < COUT; ++co)
                    acc[co] = fmaf(v, w[co], acc[co]);
            }
        }
        if (cc + 1 < NCH) write_chunk(cc + 1, 1 - (cc & 1));
        __syncthreads();
    }

    const int oy = by * TS + ty, ox = bx * TS + tx;
    const bool valid = (oy < OH) && (ox < OW);
    if (valid) {
#pragma unroll
        for (int co = 0; co < COUT; ++co)
            out[(size_t)co * OH * OW + oy * OW + ox] = acc[co];
    }

    const float scale = valid ? 1.f : 0.f;
    const int wave = tid >> 6, lane = tid & 63;
#pragma unroll
    for (int co = 0; co < COUT; ++co) {
        float s = acc[co] * scale;
        float ss = acc[co] * acc[co] * scale;
#pragma unroll
        for (int o = 32; o > 0; o >>= 1) {
            s += __shfl_down(s, o);
            ss += __shfl_down(ss, o);
        }
        if (lane == 0) { red[wave][co][0] = s; red[wave][co][1] = ss; }
    }
    __syncthreads();
    if (tid < COUT) {
        float s = red[0][tid][0] + red[1][tid][0] + red[2][tid][0] + red[3][tid][0];
        float ss = red[0][tid][1] + red[1][tid][1] + red[2][tid][1] + red[3][tid][1];
        int bl = by * gridDim.x + bx;
        partials[((size_t)bl * COUT + tid) * 2]     = s;
        partials[((size_t)bl * COUT + tid) * 2 + 1] = ss;
    }
}

// ---- gate conv: 1 gate per block (grid.z = 4), single weight stream (SGPR path),
//      raw inputs: chunks 0-3 prev_h (pad 0), chunks 4-7 y2 (pad mean), dbuf ----
__global__ __launch_bounds__(256) void conv_gates_kernel(
    const float* __restrict__ ph, const float* __restrict__ y2,
    const float* __restrict__ S2, const float* __restrict__ wt,
    const float* __restrict__ bias, float* __restrict__ out,
    float* __restrict__ partials)
{
    __shared__ float smem[2][2592];
    __shared__ float s_mean2[32];
    __shared__ float red[4][32][2];

    const int tid = threadIdx.x;
    const int tx = tid & 15, ty = tid >> 4;
    const int bx = blockIdx.x, by = blockIdx.y, z = blockIdx.z;

    if (tid < 32) s_mean2[tid] = S2[tid * 2] * (1.f / HW_);

    int goff[11], cidx[11];
#pragma unroll
    for (int r = 0; r < 11; ++r) {
        int i = tid + r * 256;
        if (i < 2592) {
            int ci = i / 324;
            int rem = i - ci * 324;
            int ly = rem / 18, lx = rem - ly * 18;
            int gy = by * TS + ly - 1, gx = bx * TS + lx - 1;
            bool ok = ((unsigned)gy < 512u) && ((unsigned)gx < 512u);
            goff[r] = ok ? (ci * HW_ + gy * 512 + gx) : -1;
            cidx[r] = ci;
        } else { goff[r] = -2; cidx[r] = 0; }
    }

    float stg[11];
    auto load_chunk = [&](int cc) {
        const float* src = (cc < 4) ? (ph + (size_t)cc * 8 * HW_)
                                    : (y2 + (size_t)(cc - 4) * 8 * HW_);
#pragma unroll
        for (int r = 0; r < 11; ++r)
            if (goff[r] >= 0) stg[r] = src[goff[r]];
    };
    auto write_chunk = [&](int cc, int buf) {
#pragma unroll
        for (int r = 0; r < 11; ++r) {
            if (goff[r] != -2) {
                float v;
                if (goff[r] >= 0) v = stg[r];
                else v = (cc < 4) ? 0.f : s_mean2[(cc - 4) * 8 + cidx[r]];
                smem[buf][tid + r * 256] = v;
            }
        }
    };

    float acc[32];
#pragma unroll
    for (int co = 0; co < 32; ++co) acc[co] = bias[z * 32 + co];

    load_chunk(0);
    __syncthreads();           // s_mean2 ready (only needed for cc>=4 writes, but cheap)
    write_chunk(0, 0);
    __syncthreads();

    const float* wz = wt + (size_t)z * 64 * 9 * 32;

#pragma unroll 1
    for (int cc = 0; cc < 8; ++cc) {
        if (cc < 7) load_chunk(cc + 1);           // latency under compute
        const float* sp = smem[cc & 1];
        const float* wc = wz + cc * 8 * 9 * 32;
#pragma unroll
        for (int ci = 0; ci < 8; ++ci) {
#pragma unroll
            for (int kk = 0; kk < 9; ++kk) {
                const int ky = kk / 3, kx = kk - ky * 3;
                float v = sp[ci * 324 + (ty + ky) * 18 + (tx + kx)];
                const float* w = wc + (ci * 9 + kk) * 32;
#pragma unroll
                for (int co = 0; co < 32; ++co)
                    acc[co] = fmaf(v, w[co], acc[co]);
            }
        }
        if (cc < 7) write_chunk(cc + 1, 1 - (cc & 1));
        __syncthreads();
    }

    const int oy = by * TS + ty, ox = bx * TS + tx;
    const size_t p = (size_t)oy * 512 + ox;
    float* oz = out + (size_t)z * 32 * HW_;
#pragma unroll
    for (int co = 0; co < 32; ++co)
        oz[(size_t)co * HW_ + p] = acc[co];

    const int wave = tid >> 6, lane = tid & 63;
#pragma unroll
    for (int co = 0; co < 32; ++co) {
        float s = acc[co], ss = acc[co] * acc[co];
#pragma unroll
        for (int o = 32; o > 0; o >>= 1) {
            s += __shfl_down(s, o);
            ss += __shfl_down(ss, o);
        }
        if (lane == 0) { red[wave][co][0] = s; red[wave][co][1] = ss; }
    }
    __syncthreads();
    if (tid < 32) {
        float s = red[0][tid][0] + red[1][tid][0] + red[2][tid][0] + red[3][tid][0];
        float ss = red[0][tid][1] + red[1][tid][1] + red[2][tid][1] + red[3][tid][1];
        int bl = z * 1024 + by * 32 + bx;
        partials[((size_t)bl * 32 + tid) * 2]     = s;
        partials[((size_t)bl * 32 + tid) * 2 + 1] = ss;
    }
}

// ---- reduce per-block partials -> per-channel (sum, sumsq) ----
__global__ __launch_bounds__(256) void reduce_kernel(const float* __restrict__ p,
                                                     float* __restrict__ sums,
                                                     int nb, int cout) {
    int c = blockIdx.x;
    int g = c / cout, co = c - g * cout;
    const float* base = p + (size_t)g * nb * cout * 2;
    float s = 0.f, ss = 0.f;
    for (int i = threadIdx.x; i < nb; i += 256) {
        s  += base[((size_t)i * cout + co) * 2];
        ss += base[((size_t)i * cout + co) * 2 + 1];
    }
#pragma unroll
    for (int o = 32; o > 0; o >>= 1) {
        s += __shfl_down(s, o);
        ss += __shfl_down(ss, o);
    }
    __shared__ float ls[4], lss[4];
    int w = threadIdx.x >> 6;
    if ((threadIdx.x & 63) == 0) { ls[w] = s; lss[w] = ss; }
    __syncthreads();
    if (threadIdx.x == 0) {
        sums[c * 2]     = ls[0] + ls[1] + ls[2] + ls[3];
        sums[c * 2 + 1] = lss[0] + lss[1] + lss[2] + lss[3];
    }
}

// ---- LSTM elementwise ----
__global__ __launch_bounds__(256) void lstm_elem_kernel(
    const float* __restrict__ gates, const float* __restrict__ S,
    const float* __restrict__ prev_c, float* __restrict__ out)
{
    __shared__ float mn[128], is_[128];
    int tid = threadIdx.x;
    if (tid < 128) {
        float s = S[tid * 2], ss = S[tid * 2 + 1];
        float m = s * (1.f / HW_);
        mn[tid] = m;
        is_[tid] = rsqrtf(ss * (1.f / HW_) - m * m + EPS_);
    }
    __syncthreads();
    size_t p = (size_t)(blockIdx.x * 256 + tid) * 4;
    for (int ch = 0; ch < 32; ++ch) {
        f4 fv = *(const f4*)(gates + (size_t)ch * HW_ + p);
        f4 iv = *(const f4*)(gates + (size_t)(32 + ch) * HW_ + p);
        f4 cv = *(const f4*)(gates + (size_t)(64 + ch) * HW_ + p);
        f4 ov = *(const f4*)(gates + (size_t)(96 + ch) * HW_ + p);
        f4 pc = *(const f4*)(prev_c + (size_t)ch * HW_ + p);
        float fm = mn[ch], fs = is_[ch];
        float im = mn[32 + ch], isd = is_[32 + ch];
        float cm = mn[64 + ch], cs = is_[64 + ch];
        float om = mn[96 + ch], os = is_[96 + ch];
        f4 nc, nh;
#pragma unroll
        for (int k = 0; k < 4; ++k) {
            float f = sigmoidf_((fv[k] - fm) * fs);
            float i = sigmoidf_((iv[k] - im) * isd);
            float c = tanhf((cv[k] - cm) * cs);
            float o = sigmoidf_((ov[k] - om) * os);
            float ncv = pc[k] * f + i * c;
            nc[k] = ncv;
            nh[k] = tanhf(ncv) * o;
        }
        *(f4*)(out + (size_t)ch * HW_ + p) = nc;
        *(f4*)(out + (size_t)32 * HW_ + (size_t)ch * HW_ + p) = nh;
    }
}

// ---- hole gather ----
__global__ void holes_kernel(const float* __restrict__ rm, const float* __restrict__ S,
                             const int* __restrict__ holes,
                             const float* __restrict__ w_oil, const float* __restrict__ b_oil,
                             const float* __restrict__ w_wat, const float* __restrict__ b_wat,
                             const float* __restrict__ w_gas, const float* __restrict__ b_gas,
                             float* __restrict__ res)
{
    int i = threadIdx.x;
    int hx = holes[i * 2], hy = holes[i * 2 + 1];
    const float invn = 1.f / (float)RMHW;
#pragma unroll
    for (int c = 0; c < 3; ++c) {
        float s = S[c * 2], ss = S[c * 2 + 1];
        float m = s * invn;
        float istd = rsqrtf(ss * invn - m * m + EPS_);
        float raw = rm[(size_t)c * RMHW + (size_t)(hx + 3) * RMH + (hy + 3)];
        float nv = (raw - m) * istd;
        float w = (c == 0) ? w_oil[0] : (c == 1) ? w_wat[0] : w_gas[0];
        float b = (c == 0) ? b_oil[0] : (c == 1) ? b_wat[0] : b_gas[0];
        res[i * 3 + c] = nv * w + b;
    }
}

extern "C" void kernel_launch(void* const* d_in, const int* in_sizes, int n_in,
                              void* d_out, int out_size, void* d_ws, size_t ws_size,
                              hipStream_t stream) {
    const float* x      = (const float*)d_in[0];
    const float* prev_c = (const float*)d_in[1];
    const float* prev_h = (const float*)d_in[2];
    const int*   holes  = (const int*)d_in[3];
    const float* w_e1 = (const float*)d_in[4];
    const float* w_e2 = (const float*)d_in[5];
    const float* w_f  = (const float*)d_in[6];
    const float* w_i  = (const float*)d_in[7];
    const float* w_c  = (const float*)d_in[8];
    const float* w_o  = (const float*)d_in[9];
    const float* w_r1 = (const float*)d_in[10];
    const float* w_r2 = (const float*)d_in[11];
    const float* w_oil = (const float*)d_in[12];
    const float* b_oil = (const float*)d_in[13];
    const float* w_wat = (const float*)d_in[14];
    const float* b_wat = (const float*)d_in[15];
    const float* w_gas = (const float*)d_in[16];
    const float* b_gas = (const float*)d_in[17];

    float* out = (float*)d_out;
    float* ws  = (float*)d_ws;

    size_t o = 0;
    float* wt_e1 = ws + o; o += 4 * 9 * 32;
    float* wt_e2 = ws + o; o += 32 * 9 * 32;
    float* wt_g  = ws + o; o += 4 * 64 * 9 * 32;
    float* wt_r1 = ws + o; o += 32 * 9 * 32;
    float* wt_r2 = ws + o; o += 32 * 9 * 3;
    float* gbias = ws + o; o += 128;
    float* y1    = ws + o; o += (size_t)32 * HW_;   // reused as r1
    float* y2    = ws + o; o += (size_t)32 * HW_;   // reused as rm
    float* gates = ws + o; o += (size_t)128 * HW_;
    float* P1 = ws + o; o += 1024 * 32 * 2;
    float* P2 = ws + o; o += 1024 * 32 * 2;
    float* P3 = ws + o; o += 4096 * 32 * 2;
    float* P4 = ws + o; o += 1024 * 32 * 2;
    float* P5 = ws + o; o += 1089 * 3 * 2;
    float* S1 = ws + o; o += 64;
    float* S2 = ws + o; o += 64;
    float* S3 = ws + o; o += 256;
    float* S4 = ws + o; o += 64;
    float* S5 = ws + o; o += 8;
    float* r1 = y1;
    float* rm = y2;

    const float invHW = 1.f / (float)HW_;
    dim3 blk(256);

    wtrans_kernel<<<dim3(5), blk, 0, stream>>>(w_e1, wt_e1, 4, 32);
    wtrans_kernel<<<dim3(36), blk, 0, stream>>>(w_e2, wt_e2, 32, 32);
    wtrans_kernel<<<dim3(72), blk, 0, stream>>>(w_f, wt_g + 0 * 64 * 9 * 32, 64, 32);
    wtrans_kernel<<<dim3(72), blk, 0, stream>>>(w_i, wt_g + 1 * 64 * 9 * 32, 64, 32);
    wtrans_kernel<<<dim3(72), blk, 0, stream>>>(w_c, wt_g + 2 * 64 * 9 * 32, 64, 32);
    wtrans_kernel<<<dim3(72), blk, 0, stream>>>(w_o, wt_g + 3 * 64 * 9 * 32, 64, 32);
    wtrans_kernel<<<dim3(36), blk, 0, stream>>>(w_r1, wt_r1, 32, 32);
    wtrans_kernel<<<dim3(4),  blk, 0, stream>>>(w_r2, wt_r2, 32, 3);

    // conv_e1: x(4ch) raw -> y1 + P1
    conv3x3_kernel<4, 32, 1, 0><<<dim3(32, 32), blk, 0, stream>>>(
        x, nullptr, wt_e1, y1, P1, H_, W_, invHW);
    reduce_kernel<<<dim3(32), blk, 0, stream>>>(P1, S1, 1024, 32);

    // conv_e2: norm+relu(y1) -> y2 + P2
    conv3x3_kernel<32, 32, 1, 2><<<dim3(32, 32), blk, 0, stream>>>(
        y1, S1, wt_e2, y2, P2, H_, W_, invHW);
    reduce_kernel<<<dim3(32), blk, 0, stream>>>(P2, S2, 1024, 32);

    // fold BN(y2) into gate weights, then 1-gate-per-block conv on raw inputs
    wgprep_kernel<<<dim3(1), dim3(128), 0, stream>>>(wt_g, S2, gbias);
    conv_gates_kernel<<<dim3(32, 32, 4), blk, 0, stream>>>(
        prev_h, y2, S2, wt_g, gbias, gates, P3);
    reduce_kernel<<<dim3(128), blk, 0, stream>>>(P3, S3, 1024, 32);

    lstm_elem_kernel<<<dim3(256), blk, 0, stream>>>(gates, S3, prev_c, out);

    // conv_r1: next_h raw -> r1 + P4
    conv3x3_kernel<32, 32, 1, 0><<<dim3(32, 32), blk, 0, stream>>>(
        out + (size_t)32 * HW_, nullptr, wt_r1, r1, P4, H_, W_, invHW);
    reduce_kernel<<<dim3(32), blk, 0, stream>>>(P4, S4, 1024, 32);

    // conv_r2: norm+relu(r1), pad=4 -> rm (3 x 518 x 518) + P5
    conv3x3_kernel<32, 3, 4, 2><<<dim3(33, 33), blk, 0, stream>>>(
        r1, S4, wt_r2, rm, P5, RMH, RMH, invHW);
    reduce_kernel<<<dim3(3), blk, 0, stream>>>(P5, S5, 1089, 3);

    holes_kernel<<<dim3(1), blk, 0, stream>>>(
        rm, S5, holes, w_oil, b_oil, w_wat, b_wat, w_gas, b_gas,
        out + (size_t)64 * HW_);
}

// Round 5
// 1198.410 us; speedup vs baseline: 34.6921x; 3.6194x over previous
//
#include <hip/hip_runtime.h>
#include <cstddef>

// ConvLSTM cell, fp32 direct conv. R5 = recovery round: exact R1 conv structure
// (single LDS buffer, inline fill addressing, 2 barriers/chunk — the shape the
// compiler schedules well; every reg-staged/dbuf variant regressed 4-8x via
// occupancy loss + lgkmcnt serialization). Deltas vs R1: BN folded into gate
// weights (pad=mean trick, validated R3/R4) and single merged wtrans launch.

typedef float f4 __attribute__((ext_vector_type(4)));

#define H_   512
#define W_   512
#define HW_  (H_ * W_)
#define EPS_ 1e-5f
#define RMH  518
#define RMHW (RMH * RMH)
#define TS   16

static __device__ __forceinline__ float sigmoidf_(float x) { return 1.f / (1.f + expf(-x)); }

// ---- merged weight transpose: [COUT][CIN][3][3] -> [CIN*9][COUT], all 8 tensors ----
static __device__ __forceinline__ void wtr(const float* __restrict__ src,
                                           float* __restrict__ dst,
                                           int cin, int cout, int idx) {
    int co = idx / (cin * 9);
    int r  = idx - co * cin * 9;
    dst[r * cout + co] = src[idx];
}

__global__ __launch_bounds__(256) void wtrans_all_kernel(
    const float* __restrict__ we1, const float* __restrict__ we2,
    const float* __restrict__ wf,  const float* __restrict__ wi,
    const float* __restrict__ wc,  const float* __restrict__ wo,
    const float* __restrict__ wr1, const float* __restrict__ wr2,
    float* __restrict__ te1, float* __restrict__ te2, float* __restrict__ tg,
    float* __restrict__ tr1, float* __restrict__ tr2)
{
    int idx = blockIdx.x * 256 + threadIdx.x;
    if (idx < 1152)        wtr(we1, te1, 4, 32, idx);
    else if (idx < 10368)  wtr(we2, te2, 32, 32, idx - 1152);
    else if (idx < 28800)  wtr(wf, tg + 0 * 18432, 64, 32, idx - 10368);
    else if (idx < 47232)  wtr(wi, tg + 1 * 18432, 64, 32, idx - 28800);
    else if (idx < 65664)  wtr(wc, tg + 2 * 18432, 64, 32, idx - 47232);
    else if (idx < 84096)  wtr(wo, tg + 3 * 18432, 64, 32, idx - 65664);
    else if (idx < 93312)  wtr(wr1, tr1, 32, 32, idx - 84096);
    else if (idx < 94176)  wtr(wr2, tr2, 32, 3, idx - 93312);
}

// ---- fold BN(x_emb) into gate weights (in place) + bias; 128 threads = (z,co) ----
__global__ void wgprep_kernel(float* __restrict__ wt, const float* __restrict__ S2,
                              float* __restrict__ bias) {
    int tid = threadIdx.x;
    int z = tid >> 5, co = tid & 31;
    __shared__ float m_[32], is_[32];
    if (tid < 32) {
        float s = S2[tid * 2], ss = S2[tid * 2 + 1];
        float m = s * (1.f / HW_);
        m_[tid] = m;
        is_[tid] = rsqrtf(ss * (1.f / HW_) - m * m + EPS_);
    }
    __syncthreads();
    float b = 0.f;
    float* wz = wt + (size_t)z * 64 * 9 * 32;
    for (int ci = 32; ci < 64; ++ci) {
        float m = m_[ci - 32], is = is_[ci - 32];
        for (int k = 0; k < 9; ++k) {
            size_t idx = (size_t)(ci * 9 + k) * 32 + co;
            float w = wz[idx] * is;
            wz[idx] = w;
            b -= m * w;   // cancels the pad=mean substitution at borders
        }
    }
    bias[tid] = b;
}

// ---- generic direct 3x3 conv, 16x16 tile — EXACT R1 structure ----
// MODE: 0 = raw input (pad 0); 2 = BN-normalize + relu at fill time (pad 0).
template <int CIN, int COUT, int PAD, int MODE>
__global__ __launch_bounds__(256) void conv3x3_kernel(
    const float* __restrict__ in, const float* __restrict__ sums,
    const float* __restrict__ wt, float* __restrict__ out,
    float* __restrict__ partials, int OH, int OW, float inv_n_in)
{
    constexpr int CH  = (CIN < 8) ? CIN : 8;
    constexpr int NCH = CIN / CH;
    constexpr int NCA = (MODE == 2) ? CIN : 1;

    __shared__ float smem[CH * 324];
    __shared__ float s_mean[NCA], s_istd[NCA];
    __shared__ float red[4][COUT][2];

    const int tid = threadIdx.x;
    const int tx = tid & 15, ty = tid >> 4;
    const int bx = blockIdx.x, by = blockIdx.y;

    if constexpr (MODE == 2) {
        if (tid < CIN) {
            float s = sums[tid * 2], ss = sums[tid * 2 + 1];
            float m = s * inv_n_in;
            s_mean[tid] = m;
            s_istd[tid] = rsqrtf(ss * inv_n_in - m * m + EPS_);
        }
    }

    float acc[COUT];
#pragma unroll
    for (int i = 0; i < COUT; ++i) acc[i] = 0.f;

#pragma unroll 1
    for (int cc = 0; cc < NCH; ++cc) {
        __syncthreads();   // smem reuse protection; also covers s_mean on first iter
        for (int i = tid; i < CH * 324; i += 256) {
            int ci = i / 324;
            int rem = i - ci * 324;
            int ly = rem / 18, lx = rem - ly * 18;
            int gy = by * TS + ly - PAD, gx = bx * TS + lx - PAD;
            float v = 0.f;
            if ((unsigned)gy < 512u && (unsigned)gx < 512u) {
                int c = cc * CH + ci;
                v = in[(size_t)c * HW_ + gy * 512 + gx];
                if constexpr (MODE == 2)
                    v = fmaxf((v - s_mean[c]) * s_istd[c], 0.f);
            }
            smem[i] = v;
        }
        __syncthreads();

        const float* wc = wt + (size_t)cc * CH * 9 * COUT;
#pragma unroll
        for (int ci = 0; ci < CH; ++ci) {
#pragma unroll
            for (int kk = 0; kk < 9; ++kk) {
                const int ky = kk / 3, kx = kk - ky * 3;
                float v = smem[ci * 324 + (ty + ky) * 18 + (tx + kx)];
                const float* w = wc + (ci * 9 + kk) * COUT;
#pragma unroll
                for (int co = 0; co < COUT; ++co)
                    acc[co] = fmaf(v, w[co], acc[co]);
            }
        }
    }

    const int oy = by * TS + ty, ox = bx * TS + tx;
    const bool valid = (oy < OH) && (ox < OW);
    if (valid) {
#pragma unroll
        for (int co = 0; co < COUT; ++co)
            out[(size_t)co * OH * OW + oy * OW + ox] = acc[co];
    }

    const float scale = valid ? 1.f : 0.f;
    const int wave = tid >> 6, lane = tid & 63;
#pragma unroll
    for (int co = 0; co < COUT; ++co) {
        float s = acc[co] * scale;
        float ss = acc[co] * acc[co] * scale;
#pragma unroll
        for (int o = 32; o > 0; o >>= 1) {
            s += __shfl_down(s, o);
            ss += __shfl_down(ss, o);
        }
        if (lane == 0) { red[wave][co][0] = s; red[wave][co][1] = ss; }
    }
    __syncthreads();
    if (tid < COUT) {
        float s = red[0][tid][0] + red[1][tid][0] + red[2][tid][0] + red[3][tid][0];
        float ss = red[0][tid][1] + red[1][tid][1] + red[2][tid][1] + red[3][tid][1];
        int bl = by * gridDim.x + bx;
        partials[((size_t)bl * COUT + tid) * 2]     = s;
        partials[((size_t)bl * COUT + tid) * 2 + 1] = ss;
    }
}

// ---- gate conv: 1 gate/block (grid.z=4), R1 flow, raw inputs + folded weights.
//      chunks 0-3 from prev_h (pad 0), chunks 4-7 from y2 (pad mean via s_pad). ----
__global__ __launch_bounds__(256) void conv_gates_kernel(
    const float* __restrict__ ph, const float* __restrict__ y2,
    const float* __restrict__ S2, const float* __restrict__ wt,
    const float* __restrict__ bias, float* __restrict__ out,
    float* __restrict__ partials)
{
    __shared__ float smem[2592];
    __shared__ float s_pad[64];
    __shared__ float red[4][32][2];

    const int tid = threadIdx.x;
    const int tx = tid & 15, ty = tid >> 4;
    const int bx = blockIdx.x, by = blockIdx.y, z = blockIdx.z;

    if (tid < 64) {
        float pv = 0.f;
        if (tid >= 32) pv = S2[(tid - 32) * 2] * (1.f / HW_);
        s_pad[tid] = pv;
    }

    float acc[32];
#pragma unroll
    for (int co = 0; co < 32; ++co) acc[co] = bias[z * 32 + co];

    const float* wz = wt + (size_t)z * 64 * 9 * 32;

#pragma unroll 1
    for (int cc = 0; cc < 8; ++cc) {
        __syncthreads();   // smem reuse protection; covers s_pad on first iter
        const float* src = (cc < 4) ? (ph + (size_t)cc * 8 * HW_)
                                    : (y2 + (size_t)(cc - 4) * 8 * HW_);
        for (int i = tid; i < 2592; i += 256) {
            int ci = i / 324;
            int rem = i - ci * 324;
            int ly = rem / 18, lx = rem - ly * 18;
            int gy = by * TS + ly - 1, gx = bx * TS + lx - 1;
            float v;
            if ((unsigned)gy < 512u && (unsigned)gx < 512u)
                v = src[(size_t)ci * HW_ + gy * 512 + gx];
            else
                v = s_pad[cc * 8 + ci];
            smem[i] = v;
        }
        __syncthreads();

        const float* wc = wz + cc * 8 * 9 * 32;
#pragma unroll
        for (int ci = 0; ci < 8; ++ci) {
#pragma unroll
            for (int kk = 0; kk < 9; ++kk) {
                const int ky = kk / 3, kx = kk - ky * 3;
                float v = smem[ci * 324 + (ty + ky) * 18 + (tx + kx)];
                const float* w = wc + (ci * 9 + kk) * 32;
#pragma unroll
                for (int co = 0; co < 32; ++co)
                    acc[co] = fmaf(v, w[co], acc[co]);
            }
        }
    }

    const int oy = by * TS + ty, ox = bx * TS + tx;
    const size_t p = (size_t)oy * 512 + ox;
    float* oz = out + (size_t)z * 32 * HW_;
#pragma unroll
    for (int co = 0; co < 32; ++co)
        oz[(size_t)co * HW_ + p] = acc[co];

    const int wave = tid >> 6, lane = tid & 63;
#pragma unroll
    for (int co = 0; co < 32; ++co) {
        float s = acc[co], ss = acc[co] * acc[co];
#pragma unroll
        for (int o = 32; o > 0; o >>= 1) {
            s += __shfl_down(s, o);
            ss += __shfl_down(ss, o);
        }
        if (lane == 0) { red[wave][co][0] = s; red[wave][co][1] = ss; }
    }
    __syncthreads();
    if (tid < 32) {
        float s = red[0][tid][0] + red[1][tid][0] + red[2][tid][0] + red[3][tid][0];
        float ss = red[0][tid][1] + red[1][tid][1] + red[2][tid][1] + red[3][tid][1];
        int bl = z * 1024 + by * 32 + bx;
        partials[((size_t)bl * 32 + tid) * 2]     = s;
        partials[((size_t)bl * 32 + tid) * 2 + 1] = ss;
    }
}

// ---- reduce per-block partials -> per-channel (sum, sumsq) ----
__global__ __launch_bounds__(256) void reduce_kernel(const float* __restrict__ p,
                                                     float* __restrict__ sums,
                                                     int nb, int cout) {
    int c = blockIdx.x;
    int g = c / cout, co = c - g * cout;
    const float* base = p + (size_t)g * nb * cout * 2;
    float s = 0.f, ss = 0.f;
    for (int i = threadIdx.x; i < nb; i += 256) {
        s  += base[((size_t)i * cout + co) * 2];
        ss += base[((size_t)i * cout + co) * 2 + 1];
    }
#pragma unroll
    for (int o = 32; o > 0; o >>= 1) {
        s += __shfl_down(s, o);
        ss += __shfl_down(ss, o);
    }
    __shared__ float ls[4], lss[4];
    int w = threadIdx.x >> 6;
    if ((threadIdx.x & 63) == 0) { ls[w] = s; lss[w] = ss; }
    __syncthreads();
    if (threadIdx.x == 0) {
        sums[c * 2]     = ls[0] + ls[1] + ls[2] + ls[3];
        sums[c * 2 + 1] = lss[0] + lss[1] + lss[2] + lss[3];
    }
}

// ---- LSTM elementwise ----
__global__ __launch_bounds__(256) void lstm_elem_kernel(
    const float* __restrict__ gates, const float* __restrict__ S,
    const float* __restrict__ prev_c, float* __restrict__ out)
{
    __shared__ float mn[128], is_[128];
    int tid = threadIdx.x;
    if (tid < 128) {
        float s = S[tid * 2], ss = S[tid * 2 + 1];
        float m = s * (1.f / HW_);
        mn[tid] = m;
        is_[tid] = rsqrtf(ss * (1.f / HW_) - m * m + EPS_);
    }
    __syncthreads();
    size_t p = (size_t)(blockIdx.x * 256 + tid) * 4;
    for (int ch = 0; ch < 32; ++ch) {
        f4 fv = *(const f4*)(gates + (size_t)ch * HW_ + p);
        f4 iv = *(const f4*)(gates + (size_t)(32 + ch) * HW_ + p);
        f4 cv = *(const f4*)(gates + (size_t)(64 + ch) * HW_ + p);
        f4 ov = *(const f4*)(gates + (size_t)(96 + ch) * HW_ + p);
        f4 pc = *(const f4*)(prev_c + (size_t)ch * HW_ + p);
        float fm = mn[ch], fs = is_[ch];
        float im = mn[32 + ch], isd = is_[32 + ch];
        float cm = mn[64 + ch], cs = is_[64 + ch];
        float om = mn[96 + ch], os = is_[96 + ch];
        f4 nc, nh;
#pragma unroll
        for (int k = 0; k < 4; ++k) {
            float f = sigmoidf_((fv[k] - fm) * fs);
            float i = sigmoidf_((iv[k] - im) * isd);
            float c = tanhf((cv[k] - cm) * cs);
            float o = sigmoidf_((ov[k] - om) * os);
            float ncv = pc[k] * f + i * c;
            nc[k] = ncv;
            nh[k] = tanhf(ncv) * o;
        }
        *(f4*)(out + (size_t)ch * HW_ + p) = nc;
        *(f4*)(out + (size_t)32 * HW_ + (size_t)ch * HW_ + p) = nh;
    }
}

// ---- hole gather ----
__global__ void holes_kernel(const float* __restrict__ rm, const float* __restrict__ S,
                             const int* __restrict__ holes,
                             const float* __restrict__ w_oil, const float* __restrict__ b_oil,
                             const float* __restrict__ w_wat, const float* __restrict__ b_wat,
                             const float* __restrict__ w_gas, const float* __restrict__ b_gas,
                             float* __restrict__ res)
{
    int i = threadIdx.x;
    int hx = holes[i * 2], hy = holes[i * 2 + 1];
    const float invn = 1.f / (float)RMHW;
#pragma unroll
    for (int c = 0; c < 3; ++c) {
        float s = S[c * 2], ss = S[c * 2 + 1];
        float m = s * invn;
        float istd = rsqrtf(ss * invn - m * m + EPS_);
        float raw = rm[(size_t)c * RMHW + (size_t)(hx + 3) * RMH + (hy + 3)];
        float nv = (raw - m) * istd;
        float w = (c == 0) ? w_oil[0] : (c == 1) ? w_wat[0] : w_gas[0];
        float b = (c == 0) ? b_oil[0] : (c == 1) ? b_wat[0] : b_gas[0];
        res[i * 3 + c] = nv * w + b;
    }
}

extern "C" void kernel_launch(void* const* d_in, const int* in_sizes, int n_in,
                              void* d_out, int out_size, void* d_ws, size_t ws_size,
                              hipStream_t stream) {
    const float* x      = (const float*)d_in[0];
    const float* prev_c = (const float*)d_in[1];
    const float* prev_h = (const float*)d_in[2];
    const int*   holes  = (const int*)d_in[3];
    const float* w_e1 = (const float*)d_in[4];
    const float* w_e2 = (const float*)d_in[5];
    const float* w_f  = (const float*)d_in[6];
    const float* w_i  = (const float*)d_in[7];
    const float* w_c  = (const float*)d_in[8];
    const float* w_o  = (const float*)d_in[9];
    const float* w_r1 = (const float*)d_in[10];
    const float* w_r2 = (const float*)d_in[11];
    const float* w_oil = (const float*)d_in[12];
    const float* b_oil = (const float*)d_in[13];
    const float* w_wat = (const float*)d_in[14];
    const float* b_wat = (const float*)d_in[15];
    const float* w_gas = (const float*)d_in[16];
    const float* b_gas = (const float*)d_in[17];

    float* out = (float*)d_out;
    float* ws  = (float*)d_ws;

    size_t o = 0;
    float* wt_e1 = ws + o; o += 4 * 9 * 32;
    float* wt_e2 = ws + o; o += 32 * 9 * 32;
    float* wt_g  = ws + o; o += 4 * 64 * 9 * 32;
    float* wt_r1 = ws + o; o += 32 * 9 * 32;
    float* wt_r2 = ws + o; o += 32 * 9 * 3;
    float* gbias = ws + o; o += 128;
    float* y1    = ws + o; o += (size_t)32 * HW_;   // reused as r1
    float* y2    = ws + o; o += (size_t)32 * HW_;   // reused as rm
    float* gates = ws + o; o += (size_t)128 * HW_;
    float* P1 = ws + o; o += 1024 * 32 * 2;
    float* P2 = ws + o; o += 1024 * 32 * 2;
    float* P3 = ws + o; o += 4096 * 32 * 2;
    float* P4 = ws + o; o += 1024 * 32 * 2;
    float* P5 = ws + o; o += 1089 * 3 * 2;
    float* S1 = ws + o; o += 64;
    float* S2 = ws + o; o += 64;
    float* S3 = ws + o; o += 256;
    float* S4 = ws + o; o += 64;
    float* S5 = ws + o; o += 8;
    float* r1 = y1;
    float* rm = y2;

    const float invHW = 1.f / (float)HW_;
    dim3 blk(256);

    // all weight transposes, one launch
    wtrans_all_kernel<<<dim3(368), blk, 0, stream>>>(
        w_e1, w_e2, w_f, w_i, w_c, w_o, w_r1, w_r2,
        wt_e1, wt_e2, wt_g, wt_r1, wt_r2);

    // conv_e1: x(4ch) raw -> y1 + P1
    conv3x3_kernel<4, 32, 1, 0><<<dim3(32, 32), blk, 0, stream>>>(
        x, nullptr, wt_e1, y1, P1, H_, W_, invHW);
    reduce_kernel<<<dim3(32), blk, 0, stream>>>(P1, S1, 1024, 32);

    // conv_e2: norm+relu(y1) -> y2 + P2
    conv3x3_kernel<32, 32, 1, 2><<<dim3(32, 32), blk, 0, stream>>>(
        y1, S1, wt_e2, y2, P2, H_, W_, invHW);
    reduce_kernel<<<dim3(32), blk, 0, stream>>>(P2, S2, 1024, 32);

    // fold BN(y2) into gate weights, then 1-gate-per-block conv on raw inputs
    wgprep_kernel<<<dim3(1), dim3(128), 0, stream>>>(wt_g, S2, gbias);
    conv_gates_kernel<<<dim3(32, 32, 4), blk, 0, stream>>>(
        prev_h, y2, S2, wt_g, gbias, gates, P3);
    reduce_kernel<<<dim3(128), blk, 0, stream>>>(P3, S3, 1024, 32);

    lstm_elem_kernel<<<dim3(256), blk, 0, stream>>>(gates, S3, prev_c, out);

    // conv_r1: next_h raw -> r1 + P4
    conv3x3_kernel<32, 32, 1, 0><<<dim3(32, 32), blk, 0, stream>>>(
        out + (size_t)32 * HW_, nullptr, wt_r1, r1, P4, H_, W_, invHW);
    reduce_kernel<<<dim3(32), blk, 0, stream>>>(P4, S4, 1024, 32);

    // conv_r2: norm+relu(r1), pad=4 -> rm (3 x 518 x 518) + P5
    conv3x3_kernel<32, 3, 4, 2><<<dim3(33, 33), blk, 0, stream>>>(
        r1, S4, wt_r2, rm, P5, RMH, RMH, invHW);
    reduce_kernel<<<dim3(3), blk, 0, stream>>>(P5, S5, 1089, 3);

    holes_kernel<<<dim3(1), blk, 0, stream>>>(
        rm, S5, holes, w_oil, b_oil, w_wat, b_wat, w_gas, b_gas,
        out + (size_t)64 * HW_);
}

// Round 6
// 1151.221 us; speedup vs baseline: 36.1142x; 1.0410x over previous
//
#include <hip/hip_runtime.h>
#include <cstddef>

// ConvLSTM cell, fp32 direct conv. R6: 2 pixels/thread on the big convs
// (gate, e2, r1): tile 32x16, acc0[32]+acc1[32], ONE SGPR weight stream shared
// by both accumulators (R3 lesson: two weight streams demote to vector loads).
// Inner-loop structure otherwise identical to the proven R1/R5 shape: single
// LDS buffer, inline fill addressing, 2 barriers/chunk. BN folded into gate
// weights (pad=mean trick); merged wtrans. e1/r2/epilogue unchanged from R5.

typedef float f4 __attribute__((ext_vector_type(4)));

#define H_   512
#define W_   512
#define HW_  (H_ * W_)
#define EPS_ 1e-5f
#define RMH  518
#define RMHW (RMH * RMH)
#define TS   16

static __device__ __forceinline__ float sigmoidf_(float x) { return 1.f / (1.f + expf(-x)); }

// ---- merged weight transpose: [COUT][CIN][3][3] -> [CIN*9][COUT], all 8 tensors ----
static __device__ __forceinline__ void wtr(const float* __restrict__ src,
                                           float* __restrict__ dst,
                                           int cin, int cout, int idx) {
    int co = idx / (cin * 9);
    int r  = idx - co * cin * 9;
    dst[r * cout + co] = src[idx];
}

__global__ __launch_bounds__(256) void wtrans_all_kernel(
    const float* __restrict__ we1, const float* __restrict__ we2,
    const float* __restrict__ wf,  const float* __restrict__ wi,
    const float* __restrict__ wc,  const float* __restrict__ wo,
    const float* __restrict__ wr1, const float* __restrict__ wr2,
    float* __restrict__ te1, float* __restrict__ te2, float* __restrict__ tg,
    float* __restrict__ tr1, float* __restrict__ tr2)
{
    int idx = blockIdx.x * 256 + threadIdx.x;
    if (idx < 1152)        wtr(we1, te1, 4, 32, idx);
    else if (idx < 10368)  wtr(we2, te2, 32, 32, idx - 1152);
    else if (idx < 28800)  wtr(wf, tg + 0 * 18432, 64, 32, idx - 10368);
    else if (idx < 47232)  wtr(wi, tg + 1 * 18432, 64, 32, idx - 28800);
    else if (idx < 65664)  wtr(wc, tg + 2 * 18432, 64, 32, idx - 47232);
    else if (idx < 84096)  wtr(wo, tg + 3 * 18432, 64, 32, idx - 65664);
    else if (idx < 93312)  wtr(wr1, tr1, 32, 32, idx - 84096);
    else if (idx < 94176)  wtr(wr2, tr2, 32, 3, idx - 93312);
}

// ---- fold BN(x_emb) into gate weights (in place) + bias; 128 threads = (z,co) ----
__global__ void wgprep_kernel(float* __restrict__ wt, const float* __restrict__ S2,
                              float* __restrict__ bias) {
    int tid = threadIdx.x;
    int z = tid >> 5, co = tid & 31;
    __shared__ float m_[32], is_[32];
    if (tid < 32) {
        float s = S2[tid * 2], ss = S2[tid * 2 + 1];
        float m = s * (1.f / HW_);
        m_[tid] = m;
        is_[tid] = rsqrtf(ss * (1.f / HW_) - m * m + EPS_);
    }
    __syncthreads();
    float b = 0.f;
    float* wz = wt + (size_t)z * 64 * 9 * 32;
    for (int ci = 32; ci < 64; ++ci) {
        float m = m_[ci - 32], is = is_[ci - 32];
        for (int k = 0; k < 9; ++k) {
            size_t idx = (size_t)(ci * 9 + k) * 32 + co;
            float w = wz[idx] * is;
            wz[idx] = w;
            b -= m * w;   // cancels the pad=mean substitution at borders
        }
    }
    bias[tid] = b;
}

// ---- generic direct 3x3 conv, 16x16 tile, 1 pixel/thread (e1, r2) ----
// MODE: 0 = raw input (pad 0); 2 = BN-normalize + relu at fill time (pad 0).
template <int CIN, int COUT, int PAD, int MODE>
__global__ __launch_bounds__(256) void conv3x3_kernel(
    const float* __restrict__ in, const float* __restrict__ sums,
    const float* __restrict__ wt, float* __restrict__ out,
    float* __restrict__ partials, int OH, int OW, float inv_n_in)
{
    constexpr int CH  = (CIN < 8) ? CIN : 8;
    constexpr int NCH = CIN / CH;
    constexpr int NCA = (MODE == 2) ? CIN : 1;

    __shared__ float smem[CH * 324];
    __shared__ float s_mean[NCA], s_istd[NCA];
    __shared__ float red[4][COUT][2];

    const int tid = threadIdx.x;
    const int tx = tid & 15, ty = tid >> 4;
    const int bx = blockIdx.x, by = blockIdx.y;

    if constexpr (MODE == 2) {
        if (tid < CIN) {
            float s = sums[tid * 2], ss = sums[tid * 2 + 1];
            float m = s * inv_n_in;
            s_mean[tid] = m;
            s_istd[tid] = rsqrtf(ss * inv_n_in - m * m + EPS_);
        }
    }

    float acc[COUT];
#pragma unroll
    for (int i = 0; i < COUT; ++i) acc[i] = 0.f;

#pragma unroll 1
    for (int cc = 0; cc < NCH; ++cc) {
        __syncthreads();
        for (int i = tid; i < CH * 324; i += 256) {
            int ci = i / 324;
            int rem = i - ci * 324;
            int ly = rem / 18, lx = rem - ly * 18;
            int gy = by * TS + ly - PAD, gx = bx * TS + lx - PAD;
            float v = 0.f;
            if ((unsigned)gy < 512u && (unsigned)gx < 512u) {
                int c = cc * CH + ci;
                v = in[(size_t)c * HW_ + gy * 512 + gx];
                if constexpr (MODE == 2)
                    v = fmaxf((v - s_mean[c]) * s_istd[c], 0.f);
            }
            smem[i] = v;
        }
        __syncthreads();

        const float* wc = wt + (size_t)cc * CH * 9 * COUT;
#pragma unroll
        for (int ci = 0; ci < CH; ++ci) {
#pragma unroll
            for (int kk = 0; kk < 9; ++kk) {
                const int ky = kk / 3, kx = kk - ky * 3;
                float v = smem[ci * 324 + (ty + ky) * 18 + (tx + kx)];
                const float* w = wc + (ci * 9 + kk) * COUT;
#pragma unroll
                for (int co = 0; co < COUT; ++co)
                    acc[co] = fmaf(v, w[co], acc[co]);
            }
        }
    }

    const int oy = by * TS + ty, ox = bx * TS + tx;
    const bool valid = (oy < OH) && (ox < OW);
    if (valid) {
#pragma unroll
        for (int co = 0; co < COUT; ++co)
            out[(size_t)co * OH * OW + oy * OW + ox] = acc[co];
    }

    const float scale = valid ? 1.f : 0.f;
    const int wave = tid >> 6, lane = tid & 63;
#pragma unroll
    for (int co = 0; co < COUT; ++co) {
        float s = acc[co] * scale;
        float ss = acc[co] * acc[co] * scale;
#pragma unroll
        for (int o = 32; o > 0; o >>= 1) {
            s += __shfl_down(s, o);
            ss += __shfl_down(ss, o);
        }
        if (lane == 0) { red[wave][co][0] = s; red[wave][co][1] = ss; }
    }
    __syncthreads();
    if (tid < COUT) {
        float s = red[0][tid][0] + red[1][tid][0] + red[2][tid][0] + red[3][tid][0];
        float ss = red[0][tid][1] + red[1][tid][1] + red[2][tid][1] + red[3][tid][1];
        int bl = by * gridDim.x + bx;
        partials[((size_t)bl * COUT + tid) * 2]     = s;
        partials[((size_t)bl * COUT + tid) * 2 + 1] = ss;
    }
}

// ---- 2-pixel/thread 3x3 conv, 32x16 tile (e2, r1): CIN=32, H=W=512, PAD=1 ----
// Thread computes pixels (bx*32+tx, oy) and (bx*32+tx+16, oy). One weight stream.
template <int COUT, int MODE>
__global__ __launch_bounds__(256, 4) void conv3x3_p2_kernel(
    const float* __restrict__ in, const float* __restrict__ sums,
    const float* __restrict__ wt, float* __restrict__ out,
    float* __restrict__ partials, float inv_n_in)
{
    constexpr int NCA = (MODE == 2) ? 32 : 1;

    __shared__ float smem[8 * 612];          // 8ch x 18rows x 34cols
    __shared__ float s_mean[NCA], s_istd[NCA];
    __shared__ float red[4][COUT][2];

    const int tid = threadIdx.x;
    const int tx = tid & 15, ty = tid >> 4;
    const int bx = blockIdx.x, by = blockIdx.y;

    if constexpr (MODE == 2) {
        if (tid < 32) {
            float s = sums[tid * 2], ss = sums[tid * 2 + 1];
            float m = s * inv_n_in;
            s_mean[tid] = m;
            s_istd[tid] = rsqrtf(ss * inv_n_in - m * m + EPS_);
        }
    }

    float acc0[COUT], acc1[COUT];
#pragma unroll
    for (int i = 0; i < COUT; ++i) { acc0[i] = 0.f; acc1[i] = 0.f; }

#pragma unroll 1
    for (int cc = 0; cc < 4; ++cc) {
        __syncthreads();
        for (int i = tid; i < 8 * 612; i += 256) {
            int ci = i / 612;
            int rem = i - ci * 612;
            int ly = rem / 34, lx = rem - ly * 34;
            int gy = by * 16 + ly - 1, gx = bx * 32 + lx - 1;
            float v = 0.f;
            if ((unsigned)gy < 512u && (unsigned)gx < 512u) {
                int c = cc * 8 + ci;
                v = in[(size_t)c * HW_ + gy * 512 + gx];
                if constexpr (MODE == 2)
                    v = fmaxf((v - s_mean[c]) * s_istd[c], 0.f);
            }
            smem[i] = v;
        }
        __syncthreads();

        const float* wc = wt + (size_t)cc * 8 * 9 * COUT;
#pragma unroll
        for (int ci = 0; ci < 8; ++ci) {
#pragma unroll
            for (int kk = 0; kk < 9; ++kk) {
                const int ky = kk / 3, kx = kk - ky * 3;
                const int base = ci * 612 + (ty + ky) * 34 + (tx + kx);
                float v0 = smem[base];
                float v1 = smem[base + 16];
                const float* w = wc + (ci * 9 + kk) * COUT;
#pragma unroll
                for (int co = 0; co < COUT; ++co) {
                    acc0[co] = fmaf(v0, w[co], acc0[co]);
                    acc1[co] = fmaf(v1, w[co], acc1[co]);
                }
            }
        }
    }

    const int oy = by * 16 + ty;
    const size_t p0 = (size_t)oy * 512 + bx * 32 + tx;
#pragma unroll
    for (int co = 0; co < COUT; ++co) {
        out[(size_t)co * HW_ + p0]      = acc0[co];
        out[(size_t)co * HW_ + p0 + 16] = acc1[co];
    }

    const int wave = tid >> 6, lane = tid & 63;
#pragma unroll
    for (int co = 0; co < COUT; ++co) {
        float s = acc0[co] + acc1[co];
        float ss = acc0[co] * acc0[co] + acc1[co] * acc1[co];
#pragma unroll
        for (int o = 32; o > 0; o >>= 1) {
            s += __shfl_down(s, o);
            ss += __shfl_down(ss, o);
        }
        if (lane == 0) { red[wave][co][0] = s; red[wave][co][1] = ss; }
    }
    __syncthreads();
    if (tid < COUT) {
        float s = red[0][tid][0] + red[1][tid][0] + red[2][tid][0] + red[3][tid][0];
        float ss = red[0][tid][1] + red[1][tid][1] + red[2][tid][1] + red[3][tid][1];
        int bl = by * gridDim.x + bx;
        partials[((size_t)bl * COUT + tid) * 2]     = s;
        partials[((size_t)bl * COUT + tid) * 2 + 1] = ss;
    }
}

// ---- gate conv: 2 pixels/thread, 1 gate/block (grid 16x32x4), folded weights.
//      chunks 0-3 from prev_h (pad 0), chunks 4-7 from y2 (pad mean via s_pad). ----
__global__ __launch_bounds__(256, 4) void conv_gates_kernel(
    const float* __restrict__ ph, const float* __restrict__ y2,
    const float* __restrict__ S2, const float* __restrict__ wt,
    const float* __restrict__ bias, float* __restrict__ out,
    float* __restrict__ partials)
{
    __shared__ float smem[8 * 612];
    __shared__ float s_pad[64];
    __shared__ float red[4][32][2];

    const int tid = threadIdx.x;
    const int tx = tid & 15, ty = tid >> 4;
    const int bx = blockIdx.x, by = blockIdx.y, z = blockIdx.z;

    if (tid < 64) {
        float pv = 0.f;
        if (tid >= 32) pv = S2[(tid - 32) * 2] * (1.f / HW_);
        s_pad[tid] = pv;
    }

    float acc0[32], acc1[32];
#pragma unroll
    for (int co = 0; co < 32; ++co) {
        float b = bias[z * 32 + co];
        acc0[co] = b; acc1[co] = b;
    }

    const float* wz = wt + (size_t)z * 64 * 9 * 32;

#pragma unroll 1
    for (int cc = 0; cc < 8; ++cc) {
        __syncthreads();   // smem reuse protection; covers s_pad on first iter
        const float* src = (cc < 4) ? (ph + (size_t)cc * 8 * HW_)
                                    : (y2 + (size_t)(cc - 4) * 8 * HW_);
        for (int i = tid; i < 8 * 612; i += 256) {
            int ci = i / 612;
            int rem = i - ci * 612;
            int ly = rem / 34, lx = rem - ly * 34;
            int gy = by * 16 + ly - 1, gx = bx * 32 + lx - 1;
            float v;
            if ((unsigned)gy < 512u && (unsigned)gx < 512u)
                v = src[(size_t)ci * HW_ + gy * 512 + gx];
            else
                v = s_pad[cc * 8 + ci];
            smem[i] = v;
        }
        __syncthreads();

        const float* wc = wz + cc * 8 * 9 * 32;
#pragma unroll
        for (int ci = 0; ci < 8; ++ci) {
#pragma unroll
            for (int kk = 0; kk < 9; ++kk) {
                const int ky = kk / 3, kx = kk - ky * 3;
                const int base = ci * 612 + (ty + ky) * 34 + (tx + kx);
                float v0 = smem[base];
                float v1 = smem[base + 16];
                const float* w = wc + (ci * 9 + kk) * 32;
#pragma unroll
                for (int co = 0; co < 32; ++co) {
                    acc0[co] = fmaf(v0, w[co], acc0[co]);
                    acc1[co] = fmaf(v1, w[co], acc1[co]);
                }
            }
        }
    }

    const int oy = by * 16 + ty;
    const size_t p0 = (size_t)oy * 512 + bx * 32 + tx;
    float* oz = out + (size_t)z * 32 * HW_;
#pragma unroll
    for (int co = 0; co < 32; ++co) {
        oz[(size_t)co * HW_ + p0]      = acc0[co];
        oz[(size_t)co * HW_ + p0 + 16] = acc1[co];
    }

    const int wave = tid >> 6, lane = tid & 63;
#pragma unroll
    for (int co = 0; co < 32; ++co) {
        float s = acc0[co] + acc1[co];
        float ss = acc0[co] * acc0[co] + acc1[co] * acc1[co];
#pragma unroll
        for (int o = 32; o > 0; o >>= 1) {
            s += __shfl_down(s, o);
            ss += __shfl_down(ss, o);
        }
        if (lane == 0) { red[wave][co][0] = s; red[wave][co][1] = ss; }
    }
    __syncthreads();
    if (tid < 32) {
        float s = red[0][tid][0] + red[1][tid][0] + red[2][tid][0] + red[3][tid][0];
        float ss = red[0][tid][1] + red[1][tid][1] + red[2][tid][1] + red[3][tid][1];
        int bl = z * 512 + by * gridDim.x + bx;
        partials[((size_t)bl * 32 + tid) * 2]     = s;
        partials[((size_t)bl * 32 + tid) * 2 + 1] = ss;
    }
}

// ---- reduce per-block partials -> per-channel (sum, sumsq) ----
__global__ __launch_bounds__(256) void reduce_kernel(const float* __restrict__ p,
                                                     float* __restrict__ sums,
                                                     int nb, int cout) {
    int c = blockIdx.x;
    int g = c / cout, co = c - g * cout;
    const float* base = p + (size_t)g * nb * cout * 2;
    float s = 0.f, ss = 0.f;
    for (int i = threadIdx.x; i < nb; i += 256) {
        s  += base[((size_t)i * cout + co) * 2];
        ss += base[((size_t)i * cout + co) * 2 + 1];
    }
#pragma unroll
    for (int o = 32; o > 0; o >>= 1) {
        s += __shfl_down(s, o);
        ss += __shfl_down(ss, o);
    }
    __shared__ float ls[4], lss[4];
    int w = threadIdx.x >> 6;
    if ((threadIdx.x & 63) == 0) { ls[w] = s; lss[w] = ss; }
    __syncthreads();
    if (threadIdx.x == 0) {
        sums[c * 2]     = ls[0] + ls[1] + ls[2] + ls[3];
        sums[c * 2 + 1] = lss[0] + lss[1] + lss[2] + lss[3];
    }
}

// ---- LSTM elementwise ----
__global__ __launch_bounds__(256) void lstm_elem_kernel(
    const float* __restrict__ gates, const float* __restrict__ S,
    const float* __restrict__ prev_c, float* __restrict__ out)
{
    __shared__ float mn[128], is_[128];
    int tid = threadIdx.x;
    if (tid < 128) {
        float s = S[tid * 2], ss = S[tid * 2 + 1];
        float m = s * (1.f / HW_);
        mn[tid] = m;
        is_[tid] = rsqrtf(ss * (1.f / HW_) - m * m + EPS_);
    }
    __syncthreads();
    size_t p = (size_t)(blockIdx.x * 256 + tid) * 4;
    for (int ch = 0; ch < 32; ++ch) {
        f4 fv = *(const f4*)(gates + (size_t)ch * HW_ + p);
        f4 iv = *(const f4*)(gates + (size_t)(32 + ch) * HW_ + p);
        f4 cv = *(const f4*)(gates + (size_t)(64 + ch) * HW_ + p);
        f4 ov = *(const f4*)(gates + (size_t)(96 + ch) * HW_ + p);
        f4 pc = *(const f4*)(prev_c + (size_t)ch * HW_ + p);
        float fm = mn[ch], fs = is_[ch];
        float im = mn[32 + ch], isd = is_[32 + ch];
        float cm = mn[64 + ch], cs = is_[64 + ch];
        float om = mn[96 + ch], os = is_[96 + ch];
        f4 nc, nh;
#pragma unroll
        for (int k = 0; k < 4; ++k) {
            float f = sigmoidf_((fv[k] - fm) * fs);
            float i = sigmoidf_((iv[k] - im) * isd);
            float c = tanhf((cv[k] - cm) * cs);
            float o = sigmoidf_((ov[k] - om) * os);
            float ncv = pc[k] * f + i * c;
            nc[k] = ncv;
            nh[k] = tanhf(ncv) * o;
        }
        *(f4*)(out + (size_t)ch * HW_ + p) = nc;
        *(f4*)(out + (size_t)32 * HW_ + (size_t)ch * HW_ + p) = nh;
    }
}

// ---- hole gather ----
__global__ void holes_kernel(const float* __restrict__ rm, const float* __restrict__ S,
                             const int* __restrict__ holes,
                             const float* __restrict__ w_oil, const float* __restrict__ b_oil,
                             const float* __restrict__ w_wat, const float* __restrict__ b_wat,
                             const float* __restrict__ w_gas, const float* __restrict__ b_gas,
                             float* __restrict__ res)
{
    int i = threadIdx.x;
    int hx = holes[i * 2], hy = holes[i * 2 + 1];
    const float invn = 1.f / (float)RMHW;
#pragma unroll
    for (int c = 0; c < 3; ++c) {
        float s = S[c * 2], ss = S[c * 2 + 1];
        float m = s * invn;
        float istd = rsqrtf(ss * invn - m * m + EPS_);
        float raw = rm[(size_t)c * RMHW + (size_t)(hx + 3) * RMH + (hy + 3)];
        float nv = (raw - m) * istd;
        float w = (c == 0) ? w_oil[0] : (c == 1) ? w_wat[0] : w_gas[0];
        float b = (c == 0) ? b_oil[0] : (c == 1) ? b_wat[0] : b_gas[0];
        res[i * 3 + c] = nv * w + b;
    }
}

extern "C" void kernel_launch(void* const* d_in, const int* in_sizes, int n_in,
                              void* d_out, int out_size, void* d_ws, size_t ws_size,
                              hipStream_t stream) {
    const float* x      = (const float*)d_in[0];
    const float* prev_c = (const float*)d_in[1];
    const float* prev_h = (const float*)d_in[2];
    const int*   holes  = (const int*)d_in[3];
    const float* w_e1 = (const float*)d_in[4];
    const float* w_e2 = (const float*)d_in[5];
    const float* w_f  = (const float*)d_in[6];
    const float* w_i  = (const float*)d_in[7];
    const float* w_c  = (const float*)d_in[8];
    const float* w_o  = (const float*)d_in[9];
    const float* w_r1 = (const float*)d_in[10];
    const float* w_r2 = (const float*)d_in[11];
    const float* w_oil = (const float*)d_in[12];
    const float* b_oil = (const float*)d_in[13];
    const float* w_wat = (const float*)d_in[14];
    const float* b_wat = (const float*)d_in[15];
    const float* w_gas = (const float*)d_in[16];
    const float* b_gas = (const float*)d_in[17];

    float* out = (float*)d_out;
    float* ws  = (float*)d_ws;

    size_t o = 0;
    float* wt_e1 = ws + o; o += 4 * 9 * 32;
    float* wt_e2 = ws + o; o += 32 * 9 * 32;
    float* wt_g  = ws + o; o += 4 * 64 * 9 * 32;
    float* wt_r1 = ws + o; o += 32 * 9 * 32;
    float* wt_r2 = ws + o; o += 32 * 9 * 3;
    float* gbias = ws + o; o += 128;
    float* y1    = ws + o; o += (size_t)32 * HW_;   // reused as r1
    float* y2    = ws + o; o += (size_t)32 * HW_;   // reused as rm
    float* gates = ws + o; o += (size_t)128 * HW_;
    float* P1 = ws + o; o += 1024 * 32 * 2;
    float* P2 = ws + o; o += 1024 * 32 * 2;
    float* P3 = ws + o; o += 4096 * 32 * 2;
    float* P4 = ws + o; o += 1024 * 32 * 2;
    float* P5 = ws + o; o += 1089 * 3 * 2;
    float* S1 = ws + o; o += 64;
    float* S2 = ws + o; o += 64;
    float* S3 = ws + o; o += 256;
    float* S4 = ws + o; o += 64;
    float* S5 = ws + o; o += 8;
    float* r1 = y1;
    float* rm = y2;

    const float invHW = 1.f / (float)HW_;
    dim3 blk(256);

    // all weight transposes, one launch
    wtrans_all_kernel<<<dim3(368), blk, 0, stream>>>(
        w_e1, w_e2, w_f, w_i, w_c, w_o, w_r1, w_r2,
        wt_e1, wt_e2, wt_g, wt_r1, wt_r2);

    // conv_e1: x(4ch) raw -> y1 + P1   (1 px/thread, 32x32 grid)
    conv3x3_kernel<4, 32, 1, 0><<<dim3(32, 32), blk, 0, stream>>>(
        x, nullptr, wt_e1, y1, P1, H_, W_, invHW);
    reduce_kernel<<<dim3(32), blk, 0, stream>>>(P1, S1, 1024, 32);

    // conv_e2: norm+relu(y1) -> y2 + P2   (2 px/thread, 16x32 grid)
    conv3x3_p2_kernel<32, 2><<<dim3(16, 32), blk, 0, stream>>>(
        y1, S1, wt_e2, y2, P2, invHW);
    reduce_kernel<<<dim3(32), blk, 0, stream>>>(P2, S2, 512, 32);

    // fold BN(y2) into gate weights, then 1-gate-per-block 2-px conv on raw inputs
    wgprep_kernel<<<dim3(1), dim3(128), 0, stream>>>(wt_g, S2, gbias);
    conv_gates_kernel<<<dim3(16, 32, 4), blk, 0, stream>>>(
        prev_h, y2, S2, wt_g, gbias, gates, P3);
    reduce_kernel<<<dim3(128), blk, 0, stream>>>(P3, S3, 512, 32);

    lstm_elem_kernel<<<dim3(256), blk, 0, stream>>>(gates, S3, prev_c, out);

    // conv_r1: next_h raw -> r1 + P4   (2 px/thread)
    conv3x3_p2_kernel<32, 0><<<dim3(16, 32), blk, 0, stream>>>(
        out + (size_t)32 * HW_, nullptr, wt_r1, r1, P4, invHW);
    reduce_kernel<<<dim3(32), blk, 0, stream>>>(P4, S4, 512, 32);

    // conv_r2: norm+relu(r1), pad=4 -> rm (3 x 518 x 518) + P5   (1 px/thread)
    conv3x3_kernel<32, 3, 4, 2><<<dim3(33, 33), blk, 0, stream>>>(
        r1, S4, wt_r2, rm, P5, RMH, RMH, invHW);
    reduce_kernel<<<dim3(3), blk, 0, stream>>>(P5, S5, 1089, 3);

    holes_kernel<<<dim3(1), blk, 0, stream>>>(
        rm, S5, holes, w_oil, b_oil, w_wat, b_wat, w_gas, b_gas,
        out + (size_t)64 * HW_);
}